// Round 7
// baseline (906.840 us; speedup 1.0000x reference)
//
#include <hip/hip_runtime.h>
#include <stdint.h>

typedef unsigned short ushort_t;
typedef short s8v __attribute__((ext_vector_type(8)));
typedef float f4v __attribute__((ext_vector_type(4)));

#define NW 200000
#define NT 100000
#define EE 500000
#define NSEG (NT + NW + NW)   // concatenated dst slots: [tok(e_wt) | wal(e_tw) | wal(e_ww)]

constexpr int HGRID = 1536;                   // hist grid-stride blocks (~4 edges/thread)
constexpr int FGRID = 1536;                   // fill grid-stride blocks
constexpr int AWG   = (NW + 255) / 256;       // 782
constexpr int ATG   = (NT + 255) / 256;       // 391
constexpr int TGRID = NT / 4;                 // 25000
constexpr int WGRID = NW / 4;                 // 50000

__device__ __forceinline__ float b2f(unsigned short u){
  union { unsigned int i; float f; } v; v.i = ((unsigned int)u) << 16; return v.f;
}
__device__ __forceinline__ unsigned short f2b(float f){
  unsigned int x = __float_as_uint(f);
  unsigned int r = x + 0x7fffu + ((x >> 16) & 1u);   // RNE
  return (unsigned short)(r >> 16);
}
__device__ __forceinline__ float ldf(const void* p, long idx, int fm){
  return fm ? ((const float*)p)[idx] : b2f(((const ushort_t*)p)[idx]);
}

// ---------------- runtime dtype probes ----------------
__global__ void detect_kern(const int* ewt, const int* etw, const int* eww,
                            const unsigned* xw_words, int* mode){
  if (threadIdx.x == 0 && blockIdx.x == 0){
    unsigned o = 0;
    for (int i = 0; i < 64; ++i)
      o |= (unsigned)ewt[2 * i + 1] | (unsigned)etw[2 * i + 1] | (unsigned)eww[2 * i + 1];
    mode[0] = (o == 0) ? 1 : 0;
    int viol = 0;
    for (int i = 0; i < 256; ++i){
      unsigned s = xw_words[i] & 0xffffu;
      unsigned e = (s >> 7) & 0xffu;
      if (!(s == 0u || s == 0x8000u || (e >= 90u && e <= 140u))) viol++;
    }
    mode[1] = (viol > 8) ? 1 : 0;
  }
}

// ------ weight transpose+convert body ------
struct TDesc { const void* src; ushort_t* dst; long ebase; int K; int N; };
struct TDesc8 { TDesc d[8]; };
__device__ __forceinline__ void transpose_body(const TDesc8& td, int fm, int b){
  int mi = b >> 6;
  TDesc t = td.d[mi];
  int e = ((b & 63) << 8) + threadIdx.x;
  if (e < t.K * t.N){
    int k = e / t.N, n = e - k * t.N;
    t.dst[n * t.K + k] = f2b(ldf(t.src, t.ebase + e, fm));
  }
}

// ------ fold att vectors into U matvec weights ------
__device__ __forceinline__ void uprep_body(const void* Wsrc0, const void* Wdst0, const void* atts0,
    const void* attd0, const void* Wsrc1, const void* Wdst1, const void* atts1, const void* attd1,
    float* Uw0, float* Ut0, float* Uw1, float* Ut1, int fm, int id){
  if (id >= (64 + 128) * 12) return;
  int layer = (id >= 64 * 12);
  int rem = layer ? id - 64 * 12 : id;
  int K = layer ? 128 : 64;
  int k = rem / 12, j = rem % 12;
  const void* Ws = layer ? Wsrc1 : Wsrc0;
  const void* Wd = layer ? Wdst1 : Wdst0;
  const void* As = layer ? atts1 : atts0;
  const void* Ad = layer ? attd1 : attd0;
  int t, h; bool src;
  if (j < 8){ const int tt[8] = {0,0,2,2,1,1,2,2}; t = tt[j]; h = j & 1; src = (j < 4); }
  else { int jj = j - 8; t = (jj < 2) ? 1 : 0; h = jj & 1; src = (jj < 2); }
  const void* W = src ? Ws : Wd;
  const void* A = src ? As : Ad;
  float acc = 0.f;
  for (int c = 0; c < 64; ++c)
    acc += ldf(W, (long)(t * K + k) * 128 + h * 64 + c, fm) * ldf(A, t * 128 + h * 64 + c, fm);
  if (j < 8) (layer ? Uw1 : Uw0)[k * 8 + j] = acc;
  else       (layer ? Ut1 : Ut0)[k * 4 + (j - 8)] = acc;
}

// ---------------- CSR build bodies (grid-stride: ~4 edges/thread, pipelined) ----------------
__device__ __forceinline__ void hist_loop(const int* ewt, const int* etw, const int* eww,
    int md, int* deg, int b, int nb){
  int t0 = b * 256 + (int)threadIdx.x;
  int step = nb * 256;
  for (int i = t0; i < 3 * EE; i += step){
    int t = i / EE, e = i - t * EE;
    const int* ep = (t == 0) ? ewt : (t == 1) ? etw : eww;
    int d = md ? ep[2 * (EE + e)] : ep[EE + e];
    int base = (t == 0) ? 0 : (t == 1) ? NT : NT + NW;
    atomicAdd(&deg[base + d], 1);
  }
}

__device__ __forceinline__ void fill_loop(const int* ewt, const int* etw, const int* eww,
    int md, int* cursor, int* adj, int b, int nb){
  int t0 = b * 256 + (int)threadIdx.x;
  int step = nb * 256;
  for (int i = t0; i < 3 * EE; i += step){
    int t = i / EE, e = i - t * EE;
    const int* ep = (t == 0) ? ewt : (t == 1) ? etw : eww;
    int s = md ? ep[2 * e] : ep[e];
    int d = md ? ep[2 * (EE + e)] : ep[EE + e];
    int base = (t == 0) ? 0 : (t == 1) ? NT : NT + NW;
    int pos = atomicAdd(&cursor[base + d], 1);
    adj[pos] = s;
  }
}

__global__ __launch_bounds__(512) void scan1(const int* deg, int* excl, int* sums){
  __shared__ int pair[512];
  int t = threadIdx.x;
  int base = blockIdx.x * 1024;
  int i0 = base + 2 * t;
  int a = (i0 < NSEG) ? deg[i0] : 0;
  int b = (i0 + 1 < NSEG) ? deg[i0 + 1] : 0;
  int ps = a + b;
  pair[t] = ps;
  __syncthreads();
  for (int off = 1; off < 512; off <<= 1){
    int v = (t >= off) ? pair[t - off] : 0;
    __syncthreads();
    if (t >= off) pair[t] += v;
    __syncthreads();
  }
  int epair = pair[t] - ps;
  if (i0 < NSEG) excl[i0] = epair;
  if (i0 + 1 < NSEG) excl[i0 + 1] = epair + a;
  if (t == 511) sums[blockIdx.x] = pair[511];
}

__global__ __launch_bounds__(512) void scan2(int* sums, int nch){
  __shared__ int s[512];
  int t = threadIdx.x;
  int orig = (t < nch) ? sums[t] : 0;
  s[t] = orig;
  __syncthreads();
  for (int off = 1; off < 512; off <<= 1){
    int v = (t >= off) ? s[t - off] : 0;
    __syncthreads();
    if (t >= off) s[t] += v;
    __syncthreads();
  }
  if (t < nch) sums[t] = s[t] - orig;
}

__global__ void scan3(int* rowptr, int* cursor, const int* sums){
  int i = blockIdx.x * 256 + threadIdx.x;
  if (i < NSEG){
    int v = rowptr[i] + sums[i >> 10];
    rowptr[i] = v; cursor[i] = v;
  }
  if (i == 0) rowptr[NSEG] = 3 * EE;
}

// -------- B-stationary MFMA GEMM body: C[M,RS] (NC cols) = A[M,K] @ Bt^T --------
template<int K, int NC, int RS, bool BIAS, bool EXTA>
__device__ __forceinline__ void gemm_body(const void* __restrict__ A, const ushort_t* __restrict__ Bt,
    const void* __restrict__ bias, ushort_t* __restrict__ C, int M, int fm, int nchunk,
    int bid, int gstr){
  constexpr int CT = NC / 16, KK = K / 32;
  int tid = threadIdx.x, lane = tid & 63, wave = tid >> 6;
  int rl = lane & 15, kq = (lane >> 4) * 8;
  s8v bfrag[CT][KK];
#pragma unroll
  for (int ct = 0; ct < CT; ++ct)
#pragma unroll
    for (int kk = 0; kk < KK; ++kk)
      bfrag[ct][kk] = *(const s8v*)(Bt + (long)(ct * 16 + rl) * K + kk * 32 + kq);
  float biasv[CT];
  if (BIAS){
#pragma unroll
    for (int ct = 0; ct < CT; ++ct) biasv[ct] = ldf(bias, ct * 16 + rl, fm);
  }
  for (int chunk = bid; chunk < nchunk; chunk += gstr){
    long m0 = (long)chunk * 128 + wave * 32;
    f4v acc[2][CT];
#pragma unroll
    for (int rt = 0; rt < 2; ++rt)
#pragma unroll
      for (int ct = 0; ct < CT; ++ct) acc[rt][ct] = (f4v){0.f, 0.f, 0.f, 0.f};
#pragma unroll
    for (int rt = 0; rt < 2; ++rt){
      long row = m0 + rt * 16 + rl;
      bool ok = row < (long)M;
#pragma unroll
      for (int kk = 0; kk < KK; ++kk){
        s8v a = (s8v){0,0,0,0,0,0,0,0};
        if (ok){
          long e = row * K + kk * 32 + kq;
          if (EXTA && fm){
            const float* p = (const float*)A + e;
            uint4 lo = *(const uint4*)p;
            uint4 hi = *(const uint4*)(p + 4);
            union { s8v v; unsigned u[4]; } t;
            t.u[0] = (unsigned)f2b(__uint_as_float(lo.x)) | ((unsigned)f2b(__uint_as_float(lo.y)) << 16);
            t.u[1] = (unsigned)f2b(__uint_as_float(lo.z)) | ((unsigned)f2b(__uint_as_float(lo.w)) << 16);
            t.u[2] = (unsigned)f2b(__uint_as_float(hi.x)) | ((unsigned)f2b(__uint_as_float(hi.y)) << 16);
            t.u[3] = (unsigned)f2b(__uint_as_float(hi.z)) | ((unsigned)f2b(__uint_as_float(hi.w)) << 16);
            a = t.v;
          } else {
            a = *(const s8v*)((const ushort_t*)A + e);
          }
        }
#pragma unroll
        for (int ct = 0; ct < CT; ++ct)
          acc[rt][ct] = __builtin_amdgcn_mfma_f32_16x16x32_bf16(a, bfrag[ct][kk], acc[rt][ct], 0, 0, 0);
      }
    }
#pragma unroll
    for (int rt = 0; rt < 2; ++rt){
      long rbase = (long)chunk * 128 + wave * 32 + rt * 16 + (lane >> 4) * 4;
#pragma unroll
      for (int ct = 0; ct < CT; ++ct){
#pragma unroll
        for (int r = 0; r < 4; ++r){
          long gm = rbase + r;
          if (gm < (long)M){
            float v = acc[rt][ct][r];
            if (BIAS) v += biasv[ct];
            C[gm * RS + ct * 16 + rl] = f2b(v);
          }
        }
      }
    }
  }
}

// ------- per-node attention scalars + exp precompute body -------
// spq layout per node: p=exp(a), q=exp(0.2a) per head. Per-edge softmax weight:
//   exp(leaky(as+ad)) = (ps*pd > 1) ? ps*pd : qs*qd   since leaky=max(x,0.2x)
template<int K, bool WAL>
__device__ __forceinline__ void a_body(const ushort_t* __restrict__ x, const float* __restrict__ U,
    float* __restrict__ dpq, float* __restrict__ spqA, float* __restrict__ spqB, int N, int n){
  constexpr int NCOL = WAL ? 8 : 4;
  if (n >= N) return;
  float acc[NCOL];
#pragma unroll
  for (int j = 0; j < NCOL; ++j) acc[j] = 0.f;
  const ushort_t* xr = x + (long)n * K;
#pragma unroll
  for (int k8 = 0; k8 < K / 8; ++k8){
    uint4 v = *(const uint4*)(xr + k8 * 8);
    unsigned uu[4] = {v.x, v.y, v.z, v.w};
#pragma unroll
    for (int i = 0; i < 4; ++i){
      float f0 = b2f((unsigned short)(uu[i] & 0xffffu));
      float f1 = b2f((unsigned short)(uu[i] >> 16));
      const float* Ur = U + (k8 * 8 + i * 2) * NCOL;
#pragma unroll
      for (int j = 0; j < NCOL; ++j) acc[j] += f0 * Ur[j] + f1 * Ur[NCOL + j];
    }
  }
  if (WAL){
    f4v tA = {__expf(acc[0]), __expf(0.2f * acc[0]), __expf(acc[1]), __expf(0.2f * acc[1])};
    *(f4v*)(spqA + (long)n * 4) = tA;                           // as_t0
    f4v tB = {__expf(acc[2]), __expf(0.2f * acc[2]), __expf(acc[3]), __expf(0.2f * acc[3])};
    *(f4v*)(spqB + (long)n * 4) = tB;                           // as_t2
    f4v d1 = {__expf(acc[4]), __expf(0.2f * acc[4]), __expf(acc[5]), __expf(0.2f * acc[5])};
    f4v d2 = {__expf(acc[6]), __expf(0.2f * acc[6]), __expf(acc[7]), __expf(0.2f * acc[7])};
    *(f4v*)(dpq + (long)n * 8) = d1;                            // ad_t1
    *(f4v*)(dpq + (long)n * 8 + 4) = d2;                        // ad_t2
  } else {
    f4v tA = {__expf(acc[0]), __expf(0.2f * acc[0]), __expf(acc[1]), __expf(0.2f * acc[1])};
    *(f4v*)(spqA + (long)n * 4) = tA;                           // as_t1
    f4v d0 = {__expf(acc[2]), __expf(0.2f * acc[2]), __expf(acc[3]), __expf(0.2f * acc[3])};
    *(f4v*)(dpq + (long)n * 4) = d0;                            // ad_t0
  }
}

// ------- exact-count gather round: all loads issued before any use -------
__device__ __forceinline__ void round_load(const int* __restrict__ adj, int j, int cnt,
    const ushort_t* __restrict__ hs, const float* __restrict__ spq, int c0, int hh,
    float2 (&pq)[8], unsigned (&h)[8]){
#pragma unroll
  for (int i = 0; i < 8; ++i){
    if (i < cnt){
      int s = adj[j + i];
      pq[i] = *(const float2*)(spq + s * 4 + hh * 2);
      h[i] = *(const unsigned*)(hs + (long)s * 128 + c0);
    }
  }
}

// ------- transcendental-free softmax accumulate (plain-exp, normalize at end) -------
__device__ __forceinline__ void round_acc(int cnt, float pd, float qd,
    const float2 (&pq)[8], const unsigned (&h)[8], float& n0, float& n1, float& den){
#pragma unroll
  for (int i = 0; i < 8; ++i){
    if (i < cnt){
      float t = pq[i].x * pd, u = pq[i].y * qd;
      float w = t > 1.f ? t : u;     // = exp(leaky_relu(as+ad, 0.2))
      den += w;
      n0 += w * b2f((unsigned short)(h[i] & 0xffffu));
      n1 += w * b2f((unsigned short)(h[i] >> 16));
    }
  }
}

__device__ __forceinline__ void classify_store(float o0, float o1, const void* W, const void* b,
    int lane, long g, void* dout, int fm){
  float w00 = ldf(W, 4 * lane + 0, fm), w01 = ldf(W, 4 * lane + 1, fm);
  float w10 = ldf(W, 4 * lane + 2, fm), w11 = ldf(W, 4 * lane + 3, fm);
  float p0 = o0 * w00 + o1 * w10;
  float p1 = o0 * w01 + o1 * w11;
#pragma unroll
  for (int off = 32; off > 0; off >>= 1){ p0 += __shfl_xor(p0, off, 64); p1 += __shfl_xor(p1, off, 64); }
  if (lane == 0){
    float r0 = p0 + ldf(b, 0, fm);
    float r1 = p1 + ldf(b, 1, fm);
    if (fm){ ((float*)dout)[g * 2] = r0; ((float*)dout)[g * 2 + 1] = r1; }
    else { ((ushort_t*)dout)[g * 2] = f2b(r0); ((ushort_t*)dout)[g * 2 + 1] = f2b(r1); }
  }
}

// ------- token-phase agg body (wave per token node) -------
template<bool FINAL>
__device__ __forceinline__ void agg_tok_body(const int* __restrict__ rowptr, const int* __restrict__ adj,
    const float* __restrict__ atd, const float* __restrict__ spq0, const ushort_t* __restrict__ hs0,
    const void* __restrict__ bsrc, ushort_t* __restrict__ xt_out,
    const void* __restrict__ clsWt, const void* __restrict__ clsbt,
    void* __restrict__ dout, int fm, int db){
  int wv = __builtin_amdgcn_readfirstlane(threadIdx.x >> 6);
  int lane = threadIdx.x & 63;
  int hh = lane >> 5, c0 = lane << 1;
  int d = db * 4 + wv;
  float2 dq = *(const float2*)(atd + (long)d * 4 + hh * 2);   // ad_t0
  int beg = rowptr[d], end = rowptr[d + 1];
  float n0 = 0.f, n1 = 0.f, den = 0.f;
  for (int j = beg; j < end; j += 8){
    int cnt = min(end - j, 8);
    float2 pq[8]; unsigned h[8];
    round_load(adj, j, cnt, hs0, spq0, c0, hh, pq, h);
    round_acc(cnt, dq.x, dq.y, pq, h, n0, n1, den);
  }
  float inv = 1.f / (den + 1e-16f);
  float o0 = n0 * inv + ldf(bsrc, c0, fm);
  float o1 = n1 * inv + ldf(bsrc, c0 + 1, fm);
  o0 = o0 > 0.f ? o0 : __expf(o0) - 1.f;   // ELU
  o1 = o1 > 0.f ? o1 : __expf(o1) - 1.f;
  if (!FINAL){
    unsigned pack = (unsigned)f2b(o0) | ((unsigned)f2b(o1) << 16);
    *(unsigned*)(xt_out + (long)d * 128 + c0) = pack;
  } else {
    classify_store(o0, o1, clsWt, clsbt, lane, (long)NW + d, dout, fm);
  }
}

// ------- wallet-phase agg (standalone): both streams, first rounds' loads fused -------
template<bool FINAL>
__global__ __launch_bounds__(256) void agg_wal(const int* __restrict__ rowptr, const int* __restrict__ adj,
    const float* __restrict__ awd, const float* __restrict__ spq1, const float* __restrict__ spq2,
    const ushort_t* __restrict__ hs1, const ushort_t* __restrict__ hs2,
    const void* __restrict__ bsrc, ushort_t* __restrict__ xw_out,
    const void* __restrict__ clsWw, const void* __restrict__ clsbw,
    void* __restrict__ dout, const int* __restrict__ mode){
  int fm = mode[1];
  int wv = __builtin_amdgcn_readfirstlane(threadIdx.x >> 6);
  int lane = threadIdx.x & 63;
  int hh = lane >> 5, c0 = lane << 1;
  int d = blockIdx.x * 4 + wv;
  float2 dq1 = *(const float2*)(awd + (long)d * 8 + hh * 2);      // ad_t1
  float2 dq2 = *(const float2*)(awd + (long)d * 8 + 4 + hh * 2);  // ad_t2
  int s1 = NT + d, s2 = NT + NW + d;
  int b1 = rowptr[s1], e1 = rowptr[s1 + 1];
  int b2 = rowptr[s2], e2 = rowptr[s2 + 1];
  int c1 = min(e1 - b1, 8), c2 = min(e2 - b2, 8);
  float n10 = 0.f, n11 = 0.f, den1 = 0.f;
  float n20 = 0.f, n21 = 0.f, den2 = 0.f;
  {
    float2 pq1[8], pq2[8]; unsigned h1[8], h2[8];
    if (c1 > 0) round_load(adj, b1, c1, hs1, spq1, c0, hh, pq1, h1);
    if (c2 > 0) round_load(adj, b2, c2, hs2, spq2, c0, hh, pq2, h2);
    if (c1 > 0) round_acc(c1, dq1.x, dq1.y, pq1, h1, n10, n11, den1);
    if (c2 > 0) round_acc(c2, dq2.x, dq2.y, pq2, h2, n20, n21, den2);
  }
  for (int j = b1 + 8; j < e1; j += 8){   // rare tails (deg > 8)
    int cnt = min(e1 - j, 8);
    float2 pq[8]; unsigned h[8];
    round_load(adj, j, cnt, hs1, spq1, c0, hh, pq, h);
    round_acc(cnt, dq1.x, dq1.y, pq, h, n10, n11, den1);
  }
  for (int j = b2 + 8; j < e2; j += 8){
    int cnt = min(e2 - j, 8);
    float2 pq[8]; unsigned h[8];
    round_load(adj, j, cnt, hs2, spq2, c0, hh, pq, h);
    round_acc(cnt, dq2.x, dq2.y, pq, h, n20, n21, den2);
  }
  float i1v = 1.f / (den1 + 1e-16f), i2v = 1.f / (den2 + 1e-16f);
  float o0 = n10 * i1v + n20 * i2v + ldf(bsrc, 128 + c0, fm)     + ldf(bsrc, 256 + c0, fm);
  float o1 = n11 * i1v + n21 * i2v + ldf(bsrc, 128 + c0 + 1, fm) + ldf(bsrc, 256 + c0 + 1, fm);
  o0 = o0 > 0.f ? o0 : __expf(o0) - 1.f;   // ELU
  o1 = o1 > 0.f ? o1 : __expf(o1) - 1.f;
  if (!FINAL){
    unsigned pack = (unsigned)f2b(o0) | ((unsigned)f2b(o1) << 16);
    *(unsigned*)(xw_out + (long)d * 128 + c0) = pack;
  } else {
    classify_store(o0, o1, clsWw, clsbw, lane, (long)d, dout, fm);
  }
}

// =========== merged launches (block-range dispatch over INDEPENDENT stages) ===========

// L-A: transpose(512) + uprep(9)
__global__ __launch_bounds__(256) void k_tu(TDesc8 td,
    const void* Wsrc0, const void* Wdst0, const void* atts0, const void* attd0,
    const void* Wsrc1, const void* Wdst1, const void* atts1, const void* attd1,
    float* Uw0, float* Ut0, float* Uw1, float* Ut1, const int* mode){
  int b = blockIdx.x, fm = mode[1];
  if (b < 512){ transpose_body(td, fm, b); return; }
  uprep_body(Wsrc0, Wdst0, atts0, attd0, Wsrc1, Wdst1, atts1, attd1,
             Uw0, Ut0, Uw1, Ut1, fm, (b - 512) * 256 + (int)threadIdx.x);
}

// L-B: in-proj gemms (512+256) || hist (grid-stride)
__global__ __launch_bounds__(256, 2) void k_pre(
    const void* xw_in, const ushort_t* BtLw, const void* lwb, ushort_t* xw0,
    const void* xt_in, const ushort_t* BtLt, const void* ltb, ushort_t* xt0,
    const int* ewt, const int* etw, const int* eww, int* deg,
    const int* mode, int ncW, int ncT){
  int b = blockIdx.x;
  if (b < 512){ gemm_body<128, 64, 64, true, true>(xw_in, BtLw, lwb, xw0, NW, mode[1], ncW, b, 512); return; }
  b -= 512;
  if (b < 256){ gemm_body<64, 64, 64, true, true>(xt_in, BtLt, ltb, xt0, NT, mode[1], ncT, b, 256); return; }
  b -= 256;
  hist_loop(ewt, etw, eww, mode[0], deg, b, HGRID);
}

// L-C: gemm hs0 L0 (512) || fill (grid-stride) || a_kern wal (782) || a_kern tok (391)
__global__ __launch_bounds__(256, 2) void k_fill(
    const ushort_t* xw0, const ushort_t* xt0, const ushort_t* BtS0w, ushort_t* hs0,
    const float* Uw0, const float* Ut0, float* awd, float* atd,
    float* spq0, float* spq1, float* spq2,
    const int* ewt, const int* etw, const int* eww, int* cursor, int* adj,
    const int* mode, int ncW){
  int b = blockIdx.x;
  if (b < 512){ gemm_body<64, 128, 128, false, false>(xw0, BtS0w, nullptr, hs0, NW, 0, ncW, b, 512); return; }
  b -= 512;
  if (b < FGRID){ fill_loop(ewt, etw, eww, mode[0], cursor, adj, b, FGRID); return; }
  b -= FGRID;
  if (b < AWG){ a_body<64, true>(xw0, Uw0, awd, spq0, spq2, NW, b * 256 + (int)threadIdx.x); return; }
  b -= AWG;
  a_body<64, false>(xt0, Ut0, atd, spq1, nullptr, NT, b * 256 + (int)threadIdx.x);
}

// L-D: gemm hs1 L0 (256) || gemm hs2 L0 (384) || agg_tok L0 (25000)
__global__ __launch_bounds__(256, 2) void k_tok0(
    const ushort_t* xt0, const ushort_t* xw0, const ushort_t* BtS0t, const ushort_t* BtS0w2,
    ushort_t* hs1, ushort_t* hs2,
    const int* rowptr, const int* adj, const float* atd, const float* spq0,
    const ushort_t* hs0, const void* b0, ushort_t* xtB,
    const int* mode, int ncT, int ncW){
  int b = blockIdx.x;
  if (b < 256){ gemm_body<64, 128, 128, false, false>(xt0, BtS0t, nullptr, hs1, NT, 0, ncT, b, 256); return; }
  b -= 256;
  if (b < 384){ gemm_body<64, 128, 128, false, false>(xw0, BtS0w2, nullptr, hs2, NW, 0, ncW, b, 384); return; }
  b -= 384;
  agg_tok_body<false>(rowptr, adj, atd, spq0, hs0, b0, xtB, nullptr, nullptr, nullptr, mode[1], b);
}

// L-F: gemm hs0 L1 (512) || a_kern wal L1 (782) || a_kern tok L1 (391)
__global__ __launch_bounds__(256, 2) void k_mid1(
    const ushort_t* xwB, const ushort_t* xtB, const ushort_t* BtS1w, ushort_t* hs0,
    const float* Uw1, const float* Ut1, float* awd, float* atd,
    float* spq0, float* spq1, float* spq2, const int* mode, int ncW){
  int b = blockIdx.x;
  if (b < 512){ gemm_body<128, 128, 128, false, false>(xwB, BtS1w, nullptr, hs0, NW, 0, ncW, b, 512); return; }
  b -= 512;
  if (b < AWG){ a_body<128, true>(xwB, Uw1, awd, spq0, spq2, NW, b * 256 + (int)threadIdx.x); return; }
  b -= AWG;
  a_body<128, false>(xtB, Ut1, atd, spq1, nullptr, NT, b * 256 + (int)threadIdx.x);
}

// L-G: gemm hs1 L1 (256) || gemm hs2 L1 (384) || FINAL token agg (25000)
// gemms (MFMA+stream) hide under the line-fill-bound token agg; agg_wal<true> consumes after.
__global__ __launch_bounds__(256, 2) void k_fin1(
    const ushort_t* xtB, const ushort_t* xwB, const ushort_t* BtS1t, const ushort_t* BtS1w2,
    ushort_t* hs1, ushort_t* hs2,
    const int* rowptr, const int* adj, const float* atd, const float* spq0,
    const ushort_t* hs0, const void* b1, const void* clsWt, const void* clsbt,
    void* dout, const int* mode, int ncT, int ncW){
  int b = blockIdx.x;
  if (b < 256){ gemm_body<128, 128, 128, false, false>(xtB, BtS1t, nullptr, hs1, NT, 0, ncT, b, 256); return; }
  b -= 256;
  if (b < 384){ gemm_body<128, 128, 128, false, false>(xwB, BtS1w2, nullptr, hs2, NW, 0, ncW, b, 384); return; }
  b -= 384;
  agg_tok_body<true>(rowptr, adj, atd, spq0, hs0, b1, nullptr, clsWt, clsbt, dout, mode[1], b);
}

extern "C" void kernel_launch(void* const* d_in, const int* in_sizes, int n_in,
                              void* d_out, int out_size, void* d_ws, size_t ws_size,
                              hipStream_t stream){
  const void* x_wallet = d_in[0];
  const void* x_token  = d_in[1];
  const void* lin_w_W  = d_in[2];
  const void* lin_w_b  = d_in[3];
  const void* lin_t_W  = d_in[4];
  const void* lin_t_b  = d_in[5];
  const void* Wsrc0    = d_in[6];
  const void* Wdst0    = d_in[7];
  const void* atts0    = d_in[8];
  const void* attd0    = d_in[9];
  const void* b0       = d_in[10];
  const void* Wsrc1    = d_in[11];
  const void* Wdst1    = d_in[12];
  const void* atts1    = d_in[13];
  const void* attd1    = d_in[14];
  const void* b1       = d_in[15];
  const void* cls_w_W  = d_in[16];
  const void* cls_w_b  = d_in[17];
  const void* cls_t_W  = d_in[18];
  const void* cls_t_b  = d_in[19];
  const int* e_wt = (const int*)d_in[20];
  const int* e_tw = (const int*)d_in[21];
  const int* e_ww = (const int*)d_in[22];

  char* ws = (char*)d_ws;
  size_t off = 0;
  auto alloc = [&](size_t bytes) -> char* {
    char* p = ws + off; off += (bytes + 255) & ~(size_t)255; return p;
  };
  int* rowptr = (int*)alloc((size_t)(NSEG + 1) * 4);
  int* deg    = (int*)alloc((size_t)(NSEG + 1) * 4);   // doubles as fill cursor after scan
  int* adj    = (int*)alloc((size_t)3 * EE * 4);
  int* sums   = (int*)alloc(512 * 4);
  int* mode   = (int*)alloc(8);
  ushort_t* BtLw = (ushort_t*)alloc(64 * 128 * 2);
  ushort_t* BtLt = (ushort_t*)alloc(64 * 64 * 2);
  ushort_t* BtS0 = (ushort_t*)alloc(3 * 128 * 64 * 2);
  ushort_t* BtS1 = (ushort_t*)alloc(3 * 128 * 128 * 2);
  float* Uw0 = (float*)alloc(64 * 8 * 4);
  float* Ut0 = (float*)alloc(64 * 4 * 4);
  float* Uw1 = (float*)alloc(128 * 8 * 4);
  float* Ut1 = (float*)alloc(128 * 4 * 4);
  float* awd = (float*)alloc((size_t)NW * 8 * 4);    // wallet dst-role pq (ad_t1, ad_t2)
  float* atd = (float*)alloc((size_t)NT * 4 * 4);    // token dst-role pq (ad_t0)
  float* spq0 = (float*)alloc((size_t)NW * 4 * 4);   // wallet src-role pq, type0
  float* spq1 = (float*)alloc((size_t)NT * 4 * 4);   // token  src-role pq, type1
  float* spq2 = (float*)alloc((size_t)NW * 4 * 4);   // wallet src-role pq, type2
  ushort_t* hs0 = (ushort_t*)alloc((size_t)NW * 128 * 2);
  ushort_t* hs1 = (ushort_t*)alloc((size_t)NT * 128 * 2);
  ushort_t* hs2 = (ushort_t*)alloc((size_t)NW * 128 * 2);
  ushort_t* xbuf = (ushort_t*)alloc(((size_t)NW + NT) * 128 * 2);
  ushort_t* xw0 = xbuf;
  ushort_t* xt0 = xbuf + (size_t)NW * 64;
  ushort_t* xwB = xbuf;                         // aliases xw0+xt0 (both dead by then)
  ushort_t* xtB = xbuf + (size_t)NW * 128;      // disjoint from xw0/xt0
  (void)in_sizes; (void)n_in;

  if (off > ws_size){
    hipMemsetAsync(d_out, 0, (size_t)out_size * 2, stream);
    return;
  }

  hipMemsetAsync(deg, 0, (size_t)NSEG * 4, stream);
  detect_kern<<<1, 64, 0, stream>>>(e_wt, e_tw, e_ww, (const unsigned*)x_wallet, mode);

  TDesc8 td;
  td.d[0] = { lin_w_W, BtLw, 0, 128, 64 };
  td.d[1] = { lin_t_W, BtLt, 0, 64, 64 };
  for (int t = 0; t < 3; ++t){
    td.d[2 + t] = { Wsrc0, BtS0 + t * 128 * 64,  (long)t * 64 * 128,  64,  128 };
    td.d[5 + t] = { Wsrc1, BtS1 + t * 128 * 128, (long)t * 128 * 128, 128, 128 };
  }
  int ncW = (NW + 127) / 128, ncT = (NT + 127) / 128;

  k_tu<<<521, 256, 0, stream>>>(td, Wsrc0, Wdst0, atts0, attd0, Wsrc1, Wdst1, atts1, attd1,
                                Uw0, Ut0, Uw1, Ut1, mode);
  k_pre<<<512 + 256 + HGRID, 256, 0, stream>>>(x_wallet, BtLw, lin_w_b, xw0,
                                               x_token, BtLt, lin_t_b, xt0,
                                               e_wt, e_tw, e_ww, deg, mode, ncW, ncT);
  int nch = (NSEG + 1023) / 1024;
  scan1<<<nch, 512, 0, stream>>>(deg, rowptr, sums);
  scan2<<<1, 512, 0, stream>>>(sums, nch);
  scan3<<<(NSEG + 255) / 256, 256, 0, stream>>>(rowptr, deg, sums);   // deg becomes cursor

  // ---- layer 0 ----
  k_fill<<<512 + FGRID + AWG + ATG, 256, 0, stream>>>(xw0, xt0, BtS0, hs0,
      Uw0, Ut0, awd, atd, spq0, spq1, spq2, e_wt, e_tw, e_ww, deg, adj, mode, ncW);
  k_tok0<<<256 + 384 + TGRID, 256, 0, stream>>>(xt0, xw0, BtS0 + 128 * 64, BtS0 + 2 * 128 * 64,
      hs1, hs2, rowptr, adj, atd, spq0, hs0, b0, xtB, mode, ncT, ncW);
  agg_wal<false><<<WGRID, 256, 0, stream>>>(rowptr, adj, awd, spq1, spq2, hs1, hs2, b0, xwB,
                                            nullptr, nullptr, nullptr, mode);

  // ---- layer 1 (classifier fused) ----
  k_mid1<<<512 + AWG + ATG, 256, 0, stream>>>(xwB, xtB, BtS1, hs0,
      Uw1, Ut1, awd, atd, spq0, spq1, spq2, mode, ncW);
  k_fin1<<<256 + 384 + TGRID, 256, 0, stream>>>(xtB, xwB, BtS1 + 128 * 128, BtS1 + 2 * 128 * 128,
      hs1, hs2, rowptr, adj, atd, spq0, hs0, b1, cls_t_W, cls_t_b, d_out, mode, ncT, ncW);
  agg_wal<true><<<WGRID, 256, 0, stream>>>(rowptr, adj, awd, spq1, spq2, hs1, hs2, b1, nullptr,
                                           cls_w_W, cls_w_b, d_out, mode);
}

// Round 8
// 806.179 us; speedup vs baseline: 1.1249x; 1.1249x over previous
//
#include <hip/hip_runtime.h>
#include <stdint.h>

typedef unsigned short ushort_t;
typedef short s8v __attribute__((ext_vector_type(8)));
typedef float f4v __attribute__((ext_vector_type(4)));

#define NW 200000
#define NT 100000
#define EE 500000
#define NSEG (NT + NW + NW)   // concatenated dst slots: [tok(e_wt) | wal(e_tw) | wal(e_ww)]

constexpr int HGRID = 1536;                   // hist grid-stride blocks (~4 edges/thread)
constexpr int FGRID = 1536;                   // fill grid-stride blocks
constexpr int AWG   = (NW + 255) / 256;       // 782
constexpr int ATG   = (NT + 255) / 256;       // 391
constexpr int TGRID = NT / 4;                 // 25000
constexpr int WGRID = NW / 4;                 // 50000

__device__ __forceinline__ float b2f(unsigned short u){
  union { unsigned int i; float f; } v; v.i = ((unsigned int)u) << 16; return v.f;
}
__device__ __forceinline__ unsigned short f2b(float f){
  unsigned int x = __float_as_uint(f);
  unsigned int r = x + 0x7fffu + ((x >> 16) & 1u);   // RNE
  return (unsigned short)(r >> 16);
}
__device__ __forceinline__ float ldf(const void* p, long idx, int fm){
  return fm ? ((const float*)p)[idx] : b2f(((const ushort_t*)p)[idx]);
}

// ---------------- runtime dtype probes ----------------
__global__ void detect_kern(const int* ewt, const int* etw, const int* eww,
                            const unsigned* xw_words, int* mode){
  if (threadIdx.x == 0 && blockIdx.x == 0){
    unsigned o = 0;
    for (int i = 0; i < 64; ++i)
      o |= (unsigned)ewt[2 * i + 1] | (unsigned)etw[2 * i + 1] | (unsigned)eww[2 * i + 1];
    mode[0] = (o == 0) ? 1 : 0;
    int viol = 0;
    for (int i = 0; i < 256; ++i){
      unsigned s = xw_words[i] & 0xffffu;
      unsigned e = (s >> 7) & 0xffu;
      if (!(s == 0u || s == 0x8000u || (e >= 90u && e <= 140u))) viol++;
    }
    mode[1] = (viol > 8) ? 1 : 0;
  }
}

// ------ weight transpose+convert body ------
struct TDesc { const void* src; ushort_t* dst; long ebase; int K; int N; };
struct TDesc8 { TDesc d[8]; };
__device__ __forceinline__ void transpose_body(const TDesc8& td, int fm, int b){
  int mi = b >> 6;
  TDesc t = td.d[mi];
  int e = ((b & 63) << 8) + threadIdx.x;
  if (e < t.K * t.N){
    int k = e / t.N, n = e - k * t.N;
    t.dst[n * t.K + k] = f2b(ldf(t.src, t.ebase + e, fm));
  }
}

// ------ fold att vectors into U matvec weights ------
__device__ __forceinline__ void uprep_body(const void* Wsrc0, const void* Wdst0, const void* atts0,
    const void* attd0, const void* Wsrc1, const void* Wdst1, const void* atts1, const void* attd1,
    float* Uw0, float* Ut0, float* Uw1, float* Ut1, int fm, int id){
  if (id >= (64 + 128) * 12) return;
  int layer = (id >= 64 * 12);
  int rem = layer ? id - 64 * 12 : id;
  int K = layer ? 128 : 64;
  int k = rem / 12, j = rem % 12;
  const void* Ws = layer ? Wsrc1 : Wsrc0;
  const void* Wd = layer ? Wdst1 : Wdst0;
  const void* As = layer ? atts1 : atts0;
  const void* Ad = layer ? attd1 : attd0;
  int t, h; bool src;
  if (j < 8){ const int tt[8] = {0,0,2,2,1,1,2,2}; t = tt[j]; h = j & 1; src = (j < 4); }
  else { int jj = j - 8; t = (jj < 2) ? 1 : 0; h = jj & 1; src = (jj < 2); }
  const void* W = src ? Ws : Wd;
  const void* A = src ? As : Ad;
  float acc = 0.f;
  for (int c = 0; c < 64; ++c)
    acc += ldf(W, (long)(t * K + k) * 128 + h * 64 + c, fm) * ldf(A, t * 128 + h * 64 + c, fm);
  if (j < 8) (layer ? Uw1 : Uw0)[k * 8 + j] = acc;
  else       (layer ? Ut1 : Ut0)[k * 4 + (j - 8)] = acc;
}

// ---------------- CSR build bodies (grid-stride: ~4 edges/thread, pipelined) ----------------
__device__ __forceinline__ void hist_loop(const int* ewt, const int* etw, const int* eww,
    int md, int* deg, int b, int nb){
  int t0 = b * 256 + (int)threadIdx.x;
  int step = nb * 256;
  for (int i = t0; i < 3 * EE; i += step){
    int t = i / EE, e = i - t * EE;
    const int* ep = (t == 0) ? ewt : (t == 1) ? etw : eww;
    int d = md ? ep[2 * (EE + e)] : ep[EE + e];
    int base = (t == 0) ? 0 : (t == 1) ? NT : NT + NW;
    atomicAdd(&deg[base + d], 1);
  }
}

__device__ __forceinline__ void fill_loop(const int* ewt, const int* etw, const int* eww,
    int md, int* cursor, int* adj, int b, int nb){
  int t0 = b * 256 + (int)threadIdx.x;
  int step = nb * 256;
  for (int i = t0; i < 3 * EE; i += step){
    int t = i / EE, e = i - t * EE;
    const int* ep = (t == 0) ? ewt : (t == 1) ? etw : eww;
    int s = md ? ep[2 * e] : ep[e];
    int d = md ? ep[2 * (EE + e)] : ep[EE + e];
    int base = (t == 0) ? 0 : (t == 1) ? NT : NT + NW;
    int pos = atomicAdd(&cursor[base + d], 1);
    adj[pos] = s;
  }
}

__global__ __launch_bounds__(512) void scan1(const int* deg, int* excl, int* sums){
  __shared__ int pair[512];
  int t = threadIdx.x;
  int base = blockIdx.x * 1024;
  int i0 = base + 2 * t;
  int a = (i0 < NSEG) ? deg[i0] : 0;
  int b = (i0 + 1 < NSEG) ? deg[i0 + 1] : 0;
  int ps = a + b;
  pair[t] = ps;
  __syncthreads();
  for (int off = 1; off < 512; off <<= 1){
    int v = (t >= off) ? pair[t - off] : 0;
    __syncthreads();
    if (t >= off) pair[t] += v;
    __syncthreads();
  }
  int epair = pair[t] - ps;
  if (i0 < NSEG) excl[i0] = epair;
  if (i0 + 1 < NSEG) excl[i0 + 1] = epair + a;
  if (t == 511) sums[blockIdx.x] = pair[511];
}

__global__ __launch_bounds__(512) void scan2(int* sums, int nch){
  __shared__ int s[512];
  int t = threadIdx.x;
  int orig = (t < nch) ? sums[t] : 0;
  s[t] = orig;
  __syncthreads();
  for (int off = 1; off < 512; off <<= 1){
    int v = (t >= off) ? s[t - off] : 0;
    __syncthreads();
    if (t >= off) s[t] += v;
    __syncthreads();
  }
  if (t < nch) sums[t] = s[t] - orig;
}

__global__ void scan3(int* rowptr, int* cursor, const int* sums){
  int i = blockIdx.x * 256 + threadIdx.x;
  if (i < NSEG){
    int v = rowptr[i] + sums[i >> 10];
    rowptr[i] = v; cursor[i] = v;
  }
  if (i == 0) rowptr[NSEG] = 3 * EE;
}

// -------- B-stationary MFMA GEMM body: C[M,RS] (NC cols) = A[M,K] @ Bt^T --------
template<int K, int NC, int RS, bool BIAS, bool EXTA>
__device__ __forceinline__ void gemm_body(const void* __restrict__ A, const ushort_t* __restrict__ Bt,
    const void* __restrict__ bias, ushort_t* __restrict__ C, int M, int fm, int nchunk,
    int bid, int gstr){
  constexpr int CT = NC / 16, KK = K / 32;
  int tid = threadIdx.x, lane = tid & 63, wave = tid >> 6;
  int rl = lane & 15, kq = (lane >> 4) * 8;
  s8v bfrag[CT][KK];
#pragma unroll
  for (int ct = 0; ct < CT; ++ct)
#pragma unroll
    for (int kk = 0; kk < KK; ++kk)
      bfrag[ct][kk] = *(const s8v*)(Bt + (long)(ct * 16 + rl) * K + kk * 32 + kq);
  float biasv[CT];
  if (BIAS){
#pragma unroll
    for (int ct = 0; ct < CT; ++ct) biasv[ct] = ldf(bias, ct * 16 + rl, fm);
  }
  for (int chunk = bid; chunk < nchunk; chunk += gstr){
    long m0 = (long)chunk * 128 + wave * 32;
    f4v acc[2][CT];
#pragma unroll
    for (int rt = 0; rt < 2; ++rt)
#pragma unroll
      for (int ct = 0; ct < CT; ++ct) acc[rt][ct] = (f4v){0.f, 0.f, 0.f, 0.f};
#pragma unroll
    for (int rt = 0; rt < 2; ++rt){
      long row = m0 + rt * 16 + rl;
      bool ok = row < (long)M;
#pragma unroll
      for (int kk = 0; kk < KK; ++kk){
        s8v a = (s8v){0,0,0,0,0,0,0,0};
        if (ok){
          long e = row * K + kk * 32 + kq;
          if (EXTA && fm){
            const float* p = (const float*)A + e;
            uint4 lo = *(const uint4*)p;
            uint4 hi = *(const uint4*)(p + 4);
            union { s8v v; unsigned u[4]; } t;
            t.u[0] = (unsigned)f2b(__uint_as_float(lo.x)) | ((unsigned)f2b(__uint_as_float(lo.y)) << 16);
            t.u[1] = (unsigned)f2b(__uint_as_float(lo.z)) | ((unsigned)f2b(__uint_as_float(lo.w)) << 16);
            t.u[2] = (unsigned)f2b(__uint_as_float(hi.x)) | ((unsigned)f2b(__uint_as_float(hi.y)) << 16);
            t.u[3] = (unsigned)f2b(__uint_as_float(hi.z)) | ((unsigned)f2b(__uint_as_float(hi.w)) << 16);
            a = t.v;
          } else {
            a = *(const s8v*)((const ushort_t*)A + e);
          }
        }
#pragma unroll
        for (int ct = 0; ct < CT; ++ct)
          acc[rt][ct] = __builtin_amdgcn_mfma_f32_16x16x32_bf16(a, bfrag[ct][kk], acc[rt][ct], 0, 0, 0);
      }
    }
#pragma unroll
    for (int rt = 0; rt < 2; ++rt){
      long rbase = (long)chunk * 128 + wave * 32 + rt * 16 + (lane >> 4) * 4;
#pragma unroll
      for (int ct = 0; ct < CT; ++ct){
#pragma unroll
        for (int r = 0; r < 4; ++r){
          long gm = rbase + r;
          if (gm < (long)M){
            float v = acc[rt][ct][r];
            if (BIAS) v += biasv[ct];
            C[gm * RS + ct * 16 + rl] = f2b(v);
          }
        }
      }
    }
  }
}

// ------- per-node attention scalars + exp precompute body -------
// spq layout per node: p=exp(a), q=exp(0.2a) per head. Per-edge softmax weight:
//   exp(leaky(as+ad)) = (ps*pd > 1) ? ps*pd : qs*qd   since leaky=max(x,0.2x)
template<int K, bool WAL>
__device__ __forceinline__ void a_body(const ushort_t* __restrict__ x, const float* __restrict__ U,
    float* __restrict__ dpq, float* __restrict__ spqA, float* __restrict__ spqB, int N, int n){
  constexpr int NCOL = WAL ? 8 : 4;
  if (n >= N) return;
  float acc[NCOL];
#pragma unroll
  for (int j = 0; j < NCOL; ++j) acc[j] = 0.f;
  const ushort_t* xr = x + (long)n * K;
#pragma unroll
  for (int k8 = 0; k8 < K / 8; ++k8){
    uint4 v = *(const uint4*)(xr + k8 * 8);
    unsigned uu[4] = {v.x, v.y, v.z, v.w};
#pragma unroll
    for (int i = 0; i < 4; ++i){
      float f0 = b2f((unsigned short)(uu[i] & 0xffffu));
      float f1 = b2f((unsigned short)(uu[i] >> 16));
      const float* Ur = U + (k8 * 8 + i * 2) * NCOL;
#pragma unroll
      for (int j = 0; j < NCOL; ++j) acc[j] += f0 * Ur[j] + f1 * Ur[NCOL + j];
    }
  }
  if (WAL){
    f4v tA = {__expf(acc[0]), __expf(0.2f * acc[0]), __expf(acc[1]), __expf(0.2f * acc[1])};
    *(f4v*)(spqA + (long)n * 4) = tA;                           // as_t0
    f4v tB = {__expf(acc[2]), __expf(0.2f * acc[2]), __expf(acc[3]), __expf(0.2f * acc[3])};
    *(f4v*)(spqB + (long)n * 4) = tB;                           // as_t2
    f4v d1 = {__expf(acc[4]), __expf(0.2f * acc[4]), __expf(acc[5]), __expf(0.2f * acc[5])};
    f4v d2 = {__expf(acc[6]), __expf(0.2f * acc[6]), __expf(acc[7]), __expf(0.2f * acc[7])};
    *(f4v*)(dpq + (long)n * 8) = d1;                            // ad_t1
    *(f4v*)(dpq + (long)n * 8 + 4) = d2;                        // ad_t2
  } else {
    f4v tA = {__expf(acc[0]), __expf(0.2f * acc[0]), __expf(acc[1]), __expf(0.2f * acc[1])};
    *(f4v*)(spqA + (long)n * 4) = tA;                           // as_t1
    f4v d0 = {__expf(acc[2]), __expf(0.2f * acc[2]), __expf(acc[3]), __expf(0.2f * acc[3])};
    *(f4v*)(dpq + (long)n * 4) = d0;                            // ad_t0
  }
}

// ------- exact-count gather round: all loads issued before any use -------
__device__ __forceinline__ void round_load(const int* __restrict__ adj, int j, int cnt,
    const ushort_t* __restrict__ hs, const float* __restrict__ spq, int c0, int hh,
    float2 (&pq)[8], unsigned (&h)[8]){
#pragma unroll
  for (int i = 0; i < 8; ++i){
    if (i < cnt){
      int s = adj[j + i];
      pq[i] = *(const float2*)(spq + s * 4 + hh * 2);
      h[i] = *(const unsigned*)(hs + (long)s * 128 + c0);
    }
  }
}

// ------- transcendental-free softmax accumulate (plain-exp, normalize at end) -------
__device__ __forceinline__ void round_acc(int cnt, float pd, float qd,
    const float2 (&pq)[8], const unsigned (&h)[8], float& n0, float& n1, float& den){
#pragma unroll
  for (int i = 0; i < 8; ++i){
    if (i < cnt){
      float t = pq[i].x * pd, u = pq[i].y * qd;
      float w = t > 1.f ? t : u;     // = exp(leaky_relu(as+ad, 0.2))
      den += w;
      n0 += w * b2f((unsigned short)(h[i] & 0xffffu));
      n1 += w * b2f((unsigned short)(h[i] >> 16));
    }
  }
}

__device__ __forceinline__ void classify_store(float o0, float o1, const void* W, const void* b,
    int lane, long g, void* dout, int fm){
  float w00 = ldf(W, 4 * lane + 0, fm), w01 = ldf(W, 4 * lane + 1, fm);
  float w10 = ldf(W, 4 * lane + 2, fm), w11 = ldf(W, 4 * lane + 3, fm);
  float p0 = o0 * w00 + o1 * w10;
  float p1 = o0 * w01 + o1 * w11;
#pragma unroll
  for (int off = 32; off > 0; off >>= 1){ p0 += __shfl_xor(p0, off, 64); p1 += __shfl_xor(p1, off, 64); }
  if (lane == 0){
    float r0 = p0 + ldf(b, 0, fm);
    float r1 = p1 + ldf(b, 1, fm);
    if (fm){ ((float*)dout)[g * 2] = r0; ((float*)dout)[g * 2 + 1] = r1; }
    else { ((ushort_t*)dout)[g * 2] = f2b(r0); ((ushort_t*)dout)[g * 2 + 1] = f2b(r1); }
  }
}

// ------- token-phase agg: STANDALONE (VGPR ~32, high occupancy — line-fill-bound) -------
template<bool FINAL>
__global__ __launch_bounds__(256) void agg_tok(const int* __restrict__ rowptr, const int* __restrict__ adj,
    const float* __restrict__ atd, const float* __restrict__ spq0, const ushort_t* __restrict__ hs0,
    const void* __restrict__ bsrc, ushort_t* __restrict__ xt_out,
    const void* __restrict__ clsWt, const void* __restrict__ clsbt,
    void* __restrict__ dout, const int* __restrict__ mode){
  int fm = mode[1];
  int wv = __builtin_amdgcn_readfirstlane(threadIdx.x >> 6);
  int lane = threadIdx.x & 63;
  int hh = lane >> 5, c0 = lane << 1;
  int d = blockIdx.x * 4 + wv;
  float2 dq = *(const float2*)(atd + (long)d * 4 + hh * 2);   // ad_t0
  int beg = rowptr[d], end = rowptr[d + 1];
  float n0 = 0.f, n1 = 0.f, den = 0.f;
  for (int j = beg; j < end; j += 8){
    int cnt = min(end - j, 8);
    float2 pq[8]; unsigned h[8];
    round_load(adj, j, cnt, hs0, spq0, c0, hh, pq, h);
    round_acc(cnt, dq.x, dq.y, pq, h, n0, n1, den);
  }
  float inv = 1.f / (den + 1e-16f);
  float o0 = n0 * inv + ldf(bsrc, c0, fm);
  float o1 = n1 * inv + ldf(bsrc, c0 + 1, fm);
  o0 = o0 > 0.f ? o0 : __expf(o0) - 1.f;   // ELU
  o1 = o1 > 0.f ? o1 : __expf(o1) - 1.f;
  if (!FINAL){
    unsigned pack = (unsigned)f2b(o0) | ((unsigned)f2b(o1) << 16);
    *(unsigned*)(xt_out + (long)d * 128 + c0) = pack;
  } else {
    classify_store(o0, o1, clsWt, clsbt, lane, (long)NW + d, dout, fm);
  }
}

// ------- wallet-phase agg (standalone): both streams, first rounds' loads fused -------
template<bool FINAL>
__global__ __launch_bounds__(256) void agg_wal(const int* __restrict__ rowptr, const int* __restrict__ adj,
    const float* __restrict__ awd, const float* __restrict__ spq1, const float* __restrict__ spq2,
    const ushort_t* __restrict__ hs1, const ushort_t* __restrict__ hs2,
    const void* __restrict__ bsrc, ushort_t* __restrict__ xw_out,
    const void* __restrict__ clsWw, const void* __restrict__ clsbw,
    void* __restrict__ dout, const int* __restrict__ mode){
  int fm = mode[1];
  int wv = __builtin_amdgcn_readfirstlane(threadIdx.x >> 6);
  int lane = threadIdx.x & 63;
  int hh = lane >> 5, c0 = lane << 1;
  int d = blockIdx.x * 4 + wv;
  float2 dq1 = *(const float2*)(awd + (long)d * 8 + hh * 2);      // ad_t1
  float2 dq2 = *(const float2*)(awd + (long)d * 8 + 4 + hh * 2);  // ad_t2
  int s1 = NT + d, s2 = NT + NW + d;
  int b1 = rowptr[s1], e1 = rowptr[s1 + 1];
  int b2 = rowptr[s2], e2 = rowptr[s2 + 1];
  int c1 = min(e1 - b1, 8), c2 = min(e2 - b2, 8);
  float n10 = 0.f, n11 = 0.f, den1 = 0.f;
  float n20 = 0.f, n21 = 0.f, den2 = 0.f;
  {
    float2 pq1[8], pq2[8]; unsigned h1[8], h2[8];
    if (c1 > 0) round_load(adj, b1, c1, hs1, spq1, c0, hh, pq1, h1);
    if (c2 > 0) round_load(adj, b2, c2, hs2, spq2, c0, hh, pq2, h2);
    if (c1 > 0) round_acc(c1, dq1.x, dq1.y, pq1, h1, n10, n11, den1);
    if (c2 > 0) round_acc(c2, dq2.x, dq2.y, pq2, h2, n20, n21, den2);
  }
  for (int j = b1 + 8; j < e1; j += 8){   // rare tails (deg > 8)
    int cnt = min(e1 - j, 8);
    float2 pq[8]; unsigned h[8];
    round_load(adj, j, cnt, hs1, spq1, c0, hh, pq, h);
    round_acc(cnt, dq1.x, dq1.y, pq, h, n10, n11, den1);
  }
  for (int j = b2 + 8; j < e2; j += 8){
    int cnt = min(e2 - j, 8);
    float2 pq[8]; unsigned h[8];
    round_load(adj, j, cnt, hs2, spq2, c0, hh, pq, h);
    round_acc(cnt, dq2.x, dq2.y, pq, h, n20, n21, den2);
  }
  float i1v = 1.f / (den1 + 1e-16f), i2v = 1.f / (den2 + 1e-16f);
  float o0 = n10 * i1v + n20 * i2v + ldf(bsrc, 128 + c0, fm)     + ldf(bsrc, 256 + c0, fm);
  float o1 = n11 * i1v + n21 * i2v + ldf(bsrc, 128 + c0 + 1, fm) + ldf(bsrc, 256 + c0 + 1, fm);
  o0 = o0 > 0.f ? o0 : __expf(o0) - 1.f;   // ELU
  o1 = o1 > 0.f ? o1 : __expf(o1) - 1.f;
  if (!FINAL){
    unsigned pack = (unsigned)f2b(o0) | ((unsigned)f2b(o1) << 16);
    *(unsigned*)(xw_out + (long)d * 128 + c0) = pack;
  } else {
    classify_store(o0, o1, clsWw, clsbw, lane, (long)d, dout, fm);
  }
}

// ====== merged launches: GEMM-VGPR-class bodies only (never merged with agg) ======

// L-A: transpose(512) + uprep(9)
__global__ __launch_bounds__(256) void k_tu(TDesc8 td,
    const void* Wsrc0, const void* Wdst0, const void* atts0, const void* attd0,
    const void* Wsrc1, const void* Wdst1, const void* atts1, const void* attd1,
    float* Uw0, float* Ut0, float* Uw1, float* Ut1, const int* mode){
  int b = blockIdx.x, fm = mode[1];
  if (b < 512){ transpose_body(td, fm, b); return; }
  uprep_body(Wsrc0, Wdst0, atts0, attd0, Wsrc1, Wdst1, atts1, attd1,
             Uw0, Ut0, Uw1, Ut1, fm, (b - 512) * 256 + (int)threadIdx.x);
}

// L-B: in-proj gemms (512+256) || hist (grid-stride)
__global__ __launch_bounds__(256, 2) void k_pre(
    const void* xw_in, const ushort_t* BtLw, const void* lwb, ushort_t* xw0,
    const void* xt_in, const ushort_t* BtLt, const void* ltb, ushort_t* xt0,
    const int* ewt, const int* etw, const int* eww, int* deg,
    const int* mode, int ncW, int ncT){
  int b = blockIdx.x;
  if (b < 512){ gemm_body<128, 64, 64, true, true>(xw_in, BtLw, lwb, xw0, NW, mode[1], ncW, b, 512); return; }
  b -= 512;
  if (b < 256){ gemm_body<64, 64, 64, true, true>(xt_in, BtLt, ltb, xt0, NT, mode[1], ncT, b, 256); return; }
  b -= 256;
  hist_loop(ewt, etw, eww, mode[0], deg, b, HGRID);
}

// L-C: ALL THREE hs gemms L0 (512+256+384) || fill (grid-stride) || a_kerns (782+391)
__global__ __launch_bounds__(256, 2) void k_gemms0(
    const ushort_t* xw0, const ushort_t* xt0,
    const ushort_t* BtS0w, const ushort_t* BtS0t, const ushort_t* BtS0w2,
    ushort_t* hs0, ushort_t* hs1, ushort_t* hs2,
    const float* Uw0, const float* Ut0, float* awd, float* atd,
    float* spq0, float* spq1, float* spq2,
    const int* ewt, const int* etw, const int* eww, int* cursor, int* adj,
    const int* mode, int ncW, int ncT){
  int b = blockIdx.x;
  if (b < 512){ gemm_body<64, 128, 128, false, false>(xw0, BtS0w, nullptr, hs0, NW, 0, ncW, b, 512); return; }
  b -= 512;
  if (b < 256){ gemm_body<64, 128, 128, false, false>(xt0, BtS0t, nullptr, hs1, NT, 0, ncT, b, 256); return; }
  b -= 256;
  if (b < 384){ gemm_body<64, 128, 128, false, false>(xw0, BtS0w2, nullptr, hs2, NW, 0, ncW, b, 384); return; }
  b -= 384;
  if (b < FGRID){ fill_loop(ewt, etw, eww, mode[0], cursor, adj, b, FGRID); return; }
  b -= FGRID;
  if (b < AWG){ a_body<64, true>(xw0, Uw0, awd, spq0, spq2, NW, b * 256 + (int)threadIdx.x); return; }
  b -= AWG;
  a_body<64, false>(xt0, Ut0, atd, spq1, nullptr, NT, b * 256 + (int)threadIdx.x);
}

// L-E: ALL THREE hs gemms L1 (512+256+384) || a_kerns L1 (782+391)
__global__ __launch_bounds__(256, 2) void k_gemms1(
    const ushort_t* xwB, const ushort_t* xtB,
    const ushort_t* BtS1w, const ushort_t* BtS1t, const ushort_t* BtS1w2,
    ushort_t* hs0, ushort_t* hs1, ushort_t* hs2,
    const float* Uw1, const float* Ut1, float* awd, float* atd,
    float* spq0, float* spq1, float* spq2, const int* mode, int ncW, int ncT){
  int b = blockIdx.x;
  if (b < 512){ gemm_body<128, 128, 128, false, false>(xwB, BtS1w, nullptr, hs0, NW, 0, ncW, b, 512); return; }
  b -= 512;
  if (b < 256){ gemm_body<128, 128, 128, false, false>(xtB, BtS1t, nullptr, hs1, NT, 0, ncT, b, 256); return; }
  b -= 256;
  if (b < 384){ gemm_body<128, 128, 128, false, false>(xwB, BtS1w2, nullptr, hs2, NW, 0, ncW, b, 384); return; }
  b -= 384;
  if (b < AWG){ a_body<128, true>(xwB, Uw1, awd, spq0, spq2, NW, b * 256 + (int)threadIdx.x); return; }
  b -= AWG;
  a_body<128, false>(xtB, Ut1, atd, spq1, nullptr, NT, b * 256 + (int)threadIdx.x);
}

extern "C" void kernel_launch(void* const* d_in, const int* in_sizes, int n_in,
                              void* d_out, int out_size, void* d_ws, size_t ws_size,
                              hipStream_t stream){
  const void* x_wallet = d_in[0];
  const void* x_token  = d_in[1];
  const void* lin_w_W  = d_in[2];
  const void* lin_w_b  = d_in[3];
  const void* lin_t_W  = d_in[4];
  const void* lin_t_b  = d_in[5];
  const void* Wsrc0    = d_in[6];
  const void* Wdst0    = d_in[7];
  const void* atts0    = d_in[8];
  const void* attd0    = d_in[9];
  const void* b0       = d_in[10];
  const void* Wsrc1    = d_in[11];
  const void* Wdst1    = d_in[12];
  const void* atts1    = d_in[13];
  const void* attd1    = d_in[14];
  const void* b1       = d_in[15];
  const void* cls_w_W  = d_in[16];
  const void* cls_w_b  = d_in[17];
  const void* cls_t_W  = d_in[18];
  const void* cls_t_b  = d_in[19];
  const int* e_wt = (const int*)d_in[20];
  const int* e_tw = (const int*)d_in[21];
  const int* e_ww = (const int*)d_in[22];

  char* ws = (char*)d_ws;
  size_t off = 0;
  auto alloc = [&](size_t bytes) -> char* {
    char* p = ws + off; off += (bytes + 255) & ~(size_t)255; return p;
  };
  int* rowptr = (int*)alloc((size_t)(NSEG + 1) * 4);
  int* deg    = (int*)alloc((size_t)(NSEG + 1) * 4);   // doubles as fill cursor after scan
  int* adj    = (int*)alloc((size_t)3 * EE * 4);
  int* sums   = (int*)alloc(512 * 4);
  int* mode   = (int*)alloc(8);
  ushort_t* BtLw = (ushort_t*)alloc(64 * 128 * 2);
  ushort_t* BtLt = (ushort_t*)alloc(64 * 64 * 2);
  ushort_t* BtS0 = (ushort_t*)alloc(3 * 128 * 64 * 2);
  ushort_t* BtS1 = (ushort_t*)alloc(3 * 128 * 128 * 2);
  float* Uw0 = (float*)alloc(64 * 8 * 4);
  float* Ut0 = (float*)alloc(64 * 4 * 4);
  float* Uw1 = (float*)alloc(128 * 8 * 4);
  float* Ut1 = (float*)alloc(128 * 4 * 4);
  float* awd = (float*)alloc((size_t)NW * 8 * 4);    // wallet dst-role pq (ad_t1, ad_t2)
  float* atd = (float*)alloc((size_t)NT * 4 * 4);    // token dst-role pq (ad_t0)
  float* spq0 = (float*)alloc((size_t)NW * 4 * 4);   // wallet src-role pq, type0
  float* spq1 = (float*)alloc((size_t)NT * 4 * 4);   // token  src-role pq, type1
  float* spq2 = (float*)alloc((size_t)NW * 4 * 4);   // wallet src-role pq, type2
  ushort_t* hs0 = (ushort_t*)alloc((size_t)NW * 128 * 2);
  ushort_t* hs1 = (ushort_t*)alloc((size_t)NT * 128 * 2);
  ushort_t* hs2 = (ushort_t*)alloc((size_t)NW * 128 * 2);
  ushort_t* xbuf = (ushort_t*)alloc(((size_t)NW + NT) * 128 * 2);
  ushort_t* xw0 = xbuf;
  ushort_t* xt0 = xbuf + (size_t)NW * 64;
  ushort_t* xwB = xbuf;                         // aliases xw0+xt0 (both dead by then)
  ushort_t* xtB = xbuf + (size_t)NW * 128;      // disjoint from xw0/xt0
  (void)in_sizes; (void)n_in;

  if (off > ws_size){
    hipMemsetAsync(d_out, 0, (size_t)out_size * 2, stream);
    return;
  }

  hipMemsetAsync(deg, 0, (size_t)NSEG * 4, stream);
  detect_kern<<<1, 64, 0, stream>>>(e_wt, e_tw, e_ww, (const unsigned*)x_wallet, mode);

  TDesc8 td;
  td.d[0] = { lin_w_W, BtLw, 0, 128, 64 };
  td.d[1] = { lin_t_W, BtLt, 0, 64, 64 };
  for (int t = 0; t < 3; ++t){
    td.d[2 + t] = { Wsrc0, BtS0 + t * 128 * 64,  (long)t * 64 * 128,  64,  128 };
    td.d[5 + t] = { Wsrc1, BtS1 + t * 128 * 128, (long)t * 128 * 128, 128, 128 };
  }
  int ncW = (NW + 127) / 128, ncT = (NT + 127) / 128;

  k_tu<<<521, 256, 0, stream>>>(td, Wsrc0, Wdst0, atts0, attd0, Wsrc1, Wdst1, atts1, attd1,
                                Uw0, Ut0, Uw1, Ut1, mode);
  k_pre<<<512 + 256 + HGRID, 256, 0, stream>>>(x_wallet, BtLw, lin_w_b, xw0,
                                               x_token, BtLt, lin_t_b, xt0,
                                               e_wt, e_tw, e_ww, deg, mode, ncW, ncT);
  int nch = (NSEG + 1023) / 1024;
  scan1<<<nch, 512, 0, stream>>>(deg, rowptr, sums);
  scan2<<<1, 512, 0, stream>>>(sums, nch);
  scan3<<<(NSEG + 255) / 256, 256, 0, stream>>>(rowptr, deg, sums);   // deg becomes cursor

  // ---- layer 0: all gemms+fill+a_kerns in one GEMM-class kernel, then aggs at full occ ----
  k_gemms0<<<512 + 256 + 384 + FGRID + AWG + ATG, 256, 0, stream>>>(xw0, xt0,
      BtS0, BtS0 + 128 * 64, BtS0 + 2 * 128 * 64, hs0, hs1, hs2,
      Uw0, Ut0, awd, atd, spq0, spq1, spq2, e_wt, e_tw, e_ww, deg, adj, mode, ncW, ncT);
  agg_tok<false><<<TGRID, 256, 0, stream>>>(rowptr, adj, atd, spq0, hs0, b0, xtB,
                                            nullptr, nullptr, nullptr, mode);
  agg_wal<false><<<WGRID, 256, 0, stream>>>(rowptr, adj, awd, spq1, spq2, hs1, hs2, b0, xwB,
                                            nullptr, nullptr, nullptr, mode);

  // ---- layer 1 (classifier fused) ----
  k_gemms1<<<512 + 256 + 384 + AWG + ATG, 256, 0, stream>>>(xwB, xtB,
      BtS1, BtS1 + 128 * 128, BtS1 + 2 * 128 * 128, hs0, hs1, hs2,
      Uw1, Ut1, awd, atd, spq0, spq1, spq2, mode, ncW, ncT);
  agg_tok<true><<<TGRID, 256, 0, stream>>>(rowptr, adj, atd, spq0, hs0, b1, nullptr,
                                           cls_t_W, cls_t_b, d_out, mode);
  agg_wal<true><<<WGRID, 256, 0, stream>>>(rowptr, adj, awd, spq1, spq2, hs1, hs2, b1, nullptr,
                                           cls_w_W, cls_w_b, d_out, mode);
}

// Round 9
// 795.627 us; speedup vs baseline: 1.1398x; 1.0133x over previous
//
#include <hip/hip_runtime.h>
#include <stdint.h>

typedef unsigned short ushort_t;
typedef short s8v __attribute__((ext_vector_type(8)));
typedef float f4v __attribute__((ext_vector_type(4)));

#define NW 200000
#define NT 100000
#define EE 500000
#define NSEG (NT + NW + NW)   // concatenated dst slots: [tok(e_wt) | wal(e_tw) | wal(e_ww)]

constexpr int HGRID = 1536;                   // hist grid-stride blocks (~4 edges/thread)
constexpr int FGRID = 1536;                   // fill grid-stride blocks
constexpr int AWG   = (NW + 255) / 256;       // 782
constexpr int ATG   = (NT + 255) / 256;       // 391
constexpr int TGRID = NT / 4;                 // 25000
constexpr int WGRID = NW / 4;                 // 50000

__device__ __forceinline__ float b2f(unsigned short u){
  union { unsigned int i; float f; } v; v.i = ((unsigned int)u) << 16; return v.f;
}
__device__ __forceinline__ unsigned short f2b(float f){
  unsigned int x = __float_as_uint(f);
  unsigned int r = x + 0x7fffu + ((x >> 16) & 1u);   // RNE
  return (unsigned short)(r >> 16);
}
__device__ __forceinline__ float ldf(const void* p, long idx, int fm){
  return fm ? ((const float*)p)[idx] : b2f(((const ushort_t*)p)[idx]);
}

// ---------------- runtime dtype probes ----------------
__global__ void detect_kern(const int* ewt, const int* etw, const int* eww,
                            const unsigned* xw_words, int* mode){
  if (threadIdx.x == 0 && blockIdx.x == 0){
    unsigned o = 0;
    for (int i = 0; i < 64; ++i)
      o |= (unsigned)ewt[2 * i + 1] | (unsigned)etw[2 * i + 1] | (unsigned)eww[2 * i + 1];
    mode[0] = (o == 0) ? 1 : 0;
    int viol = 0;
    for (int i = 0; i < 256; ++i){
      unsigned s = xw_words[i] & 0xffffu;
      unsigned e = (s >> 7) & 0xffu;
      if (!(s == 0u || s == 0x8000u || (e >= 90u && e <= 140u))) viol++;
    }
    mode[1] = (viol > 8) ? 1 : 0;
  }
}

// ------ weight transpose+convert body ------
struct TDesc { const void* src; ushort_t* dst; long ebase; int K; int N; };
struct TDesc8 { TDesc d[8]; };
__device__ __forceinline__ void transpose_body(const TDesc8& td, int fm, int b){
  int mi = b >> 6;
  TDesc t = td.d[mi];
  int e = ((b & 63) << 8) + threadIdx.x;
  if (e < t.K * t.N){
    int k = e / t.N, n = e - k * t.N;
    t.dst[n * t.K + k] = f2b(ldf(t.src, t.ebase + e, fm));
  }
}

// ------ fold att vectors into U matvec weights ------
__device__ __forceinline__ void uprep_body(const void* Wsrc0, const void* Wdst0, const void* atts0,
    const void* attd0, const void* Wsrc1, const void* Wdst1, const void* atts1, const void* attd1,
    float* Uw0, float* Ut0, float* Uw1, float* Ut1, int fm, int id){
  if (id >= (64 + 128) * 12) return;
  int layer = (id >= 64 * 12);
  int rem = layer ? id - 64 * 12 : id;
  int K = layer ? 128 : 64;
  int k = rem / 12, j = rem % 12;
  const void* Ws = layer ? Wsrc1 : Wsrc0;
  const void* Wd = layer ? Wdst1 : Wdst0;
  const void* As = layer ? atts1 : atts0;
  const void* Ad = layer ? attd1 : attd0;
  int t, h; bool src;
  if (j < 8){ const int tt[8] = {0,0,2,2,1,1,2,2}; t = tt[j]; h = j & 1; src = (j < 4); }
  else { int jj = j - 8; t = (jj < 2) ? 1 : 0; h = jj & 1; src = (jj < 2); }
  const void* W = src ? Ws : Wd;
  const void* A = src ? As : Ad;
  float acc = 0.f;
  for (int c = 0; c < 64; ++c)
    acc += ldf(W, (long)(t * K + k) * 128 + h * 64 + c, fm) * ldf(A, t * 128 + h * 64 + c, fm);
  if (j < 8) (layer ? Uw1 : Uw0)[k * 8 + j] = acc;
  else       (layer ? Ut1 : Ut0)[k * 4 + (j - 8)] = acc;
}

// ---------------- CSR build bodies (grid-stride: ~4 edges/thread, pipelined) ----------------
__device__ __forceinline__ void hist_loop(const int* ewt, const int* etw, const int* eww,
    int md, int* deg, int b, int nb){
  int t0 = b * 256 + (int)threadIdx.x;
  int step = nb * 256;
  for (int i = t0; i < 3 * EE; i += step){
    int t = i / EE, e = i - t * EE;
    const int* ep = (t == 0) ? ewt : (t == 1) ? etw : eww;
    int d = md ? ep[2 * (EE + e)] : ep[EE + e];
    int base = (t == 0) ? 0 : (t == 1) ? NT : NT + NW;
    atomicAdd(&deg[base + d], 1);
  }
}

__device__ __forceinline__ void fill_loop(const int* ewt, const int* etw, const int* eww,
    int md, int* cursor, int* adj, int b, int nb){
  int t0 = b * 256 + (int)threadIdx.x;
  int step = nb * 256;
  for (int i = t0; i < 3 * EE; i += step){
    int t = i / EE, e = i - t * EE;
    const int* ep = (t == 0) ? ewt : (t == 1) ? etw : eww;
    int s = md ? ep[2 * e] : ep[e];
    int d = md ? ep[2 * (EE + e)] : ep[EE + e];
    int base = (t == 0) ? 0 : (t == 1) ? NT : NT + NW;
    int pos = atomicAdd(&cursor[base + d], 1);
    adj[pos] = s;
  }
}

__global__ __launch_bounds__(512) void scan1(const int* deg, int* excl, int* sums){
  __shared__ int pair[512];
  int t = threadIdx.x;
  int base = blockIdx.x * 1024;
  int i0 = base + 2 * t;
  int a = (i0 < NSEG) ? deg[i0] : 0;
  int b = (i0 + 1 < NSEG) ? deg[i0 + 1] : 0;
  int ps = a + b;
  pair[t] = ps;
  __syncthreads();
  for (int off = 1; off < 512; off <<= 1){
    int v = (t >= off) ? pair[t - off] : 0;
    __syncthreads();
    if (t >= off) pair[t] += v;
    __syncthreads();
  }
  int epair = pair[t] - ps;
  if (i0 < NSEG) excl[i0] = epair;
  if (i0 + 1 < NSEG) excl[i0 + 1] = epair + a;
  if (t == 511) sums[blockIdx.x] = pair[511];
}

__global__ __launch_bounds__(512) void scan2(int* sums, int nch){
  __shared__ int s[512];
  int t = threadIdx.x;
  int orig = (t < nch) ? sums[t] : 0;
  s[t] = orig;
  __syncthreads();
  for (int off = 1; off < 512; off <<= 1){
    int v = (t >= off) ? s[t - off] : 0;
    __syncthreads();
    if (t >= off) s[t] += v;
    __syncthreads();
  }
  if (t < nch) sums[t] = s[t] - orig;
}

__global__ void scan3(int* rowptr, int* cursor, const int* sums){
  int i = blockIdx.x * 256 + threadIdx.x;
  if (i < NSEG){
    int v = rowptr[i] + sums[i >> 10];
    rowptr[i] = v; cursor[i] = v;
  }
  if (i == 0) rowptr[NSEG] = 3 * EE;
}

// -------- B-stationary MFMA GEMM body: C[M,RS] (NC cols) = A[M,K] @ Bt^T --------
template<int K, int NC, int RS, bool BIAS, bool EXTA>
__device__ __forceinline__ void gemm_body(const void* __restrict__ A, const ushort_t* __restrict__ Bt,
    const void* __restrict__ bias, ushort_t* __restrict__ C, int M, int fm, int nchunk,
    int bid, int gstr){
  constexpr int CT = NC / 16, KK = K / 32;
  int tid = threadIdx.x, lane = tid & 63, wave = tid >> 6;
  int rl = lane & 15, kq = (lane >> 4) * 8;
  s8v bfrag[CT][KK];
#pragma unroll
  for (int ct = 0; ct < CT; ++ct)
#pragma unroll
    for (int kk = 0; kk < KK; ++kk)
      bfrag[ct][kk] = *(const s8v*)(Bt + (long)(ct * 16 + rl) * K + kk * 32 + kq);
  float biasv[CT];
  if (BIAS){
#pragma unroll
    for (int ct = 0; ct < CT; ++ct) biasv[ct] = ldf(bias, ct * 16 + rl, fm);
  }
  for (int chunk = bid; chunk < nchunk; chunk += gstr){
    long m0 = (long)chunk * 128 + wave * 32;
    f4v acc[2][CT];
#pragma unroll
    for (int rt = 0; rt < 2; ++rt)
#pragma unroll
      for (int ct = 0; ct < CT; ++ct) acc[rt][ct] = (f4v){0.f, 0.f, 0.f, 0.f};
#pragma unroll
    for (int rt = 0; rt < 2; ++rt){
      long row = m0 + rt * 16 + rl;
      bool ok = row < (long)M;
#pragma unroll
      for (int kk = 0; kk < KK; ++kk){
        s8v a = (s8v){0,0,0,0,0,0,0,0};
        if (ok){
          long e = row * K + kk * 32 + kq;
          if (EXTA && fm){
            const float* p = (const float*)A + e;
            uint4 lo = *(const uint4*)p;
            uint4 hi = *(const uint4*)(p + 4);
            union { s8v v; unsigned u[4]; } t;
            t.u[0] = (unsigned)f2b(__uint_as_float(lo.x)) | ((unsigned)f2b(__uint_as_float(lo.y)) << 16);
            t.u[1] = (unsigned)f2b(__uint_as_float(lo.z)) | ((unsigned)f2b(__uint_as_float(lo.w)) << 16);
            t.u[2] = (unsigned)f2b(__uint_as_float(hi.x)) | ((unsigned)f2b(__uint_as_float(hi.y)) << 16);
            t.u[3] = (unsigned)f2b(__uint_as_float(hi.z)) | ((unsigned)f2b(__uint_as_float(hi.w)) << 16);
            a = t.v;
          } else {
            a = *(const s8v*)((const ushort_t*)A + e);
          }
        }
#pragma unroll
        for (int ct = 0; ct < CT; ++ct)
          acc[rt][ct] = __builtin_amdgcn_mfma_f32_16x16x32_bf16(a, bfrag[ct][kk], acc[rt][ct], 0, 0, 0);
      }
    }
#pragma unroll
    for (int rt = 0; rt < 2; ++rt){
      long rbase = (long)chunk * 128 + wave * 32 + rt * 16 + (lane >> 4) * 4;
#pragma unroll
      for (int ct = 0; ct < CT; ++ct){
#pragma unroll
        for (int r = 0; r < 4; ++r){
          long gm = rbase + r;
          if (gm < (long)M){
            float v = acc[rt][ct][r];
            if (BIAS) v += biasv[ct];
            C[gm * RS + ct * 16 + rl] = f2b(v);
          }
        }
      }
    }
  }
}

// ------- per-node attention scalars + exp precompute body -------
// spq layout per node: p=exp(a), q=exp(0.2a) per head. Per-edge softmax weight:
//   exp(leaky(as+ad)) = (ps*pd > 1) ? ps*pd : qs*qd   since leaky=max(x,0.2x)
template<int K, bool WAL>
__device__ __forceinline__ void a_body(const ushort_t* __restrict__ x, const float* __restrict__ U,
    float* __restrict__ dpq, float* __restrict__ spqA, float* __restrict__ spqB, int N, int n){
  constexpr int NCOL = WAL ? 8 : 4;
  if (n >= N) return;
  float acc[NCOL];
#pragma unroll
  for (int j = 0; j < NCOL; ++j) acc[j] = 0.f;
  const ushort_t* xr = x + (long)n * K;
#pragma unroll
  for (int k8 = 0; k8 < K / 8; ++k8){
    uint4 v = *(const uint4*)(xr + k8 * 8);
    unsigned uu[4] = {v.x, v.y, v.z, v.w};
#pragma unroll
    for (int i = 0; i < 4; ++i){
      float f0 = b2f((unsigned short)(uu[i] & 0xffffu));
      float f1 = b2f((unsigned short)(uu[i] >> 16));
      const float* Ur = U + (k8 * 8 + i * 2) * NCOL;
#pragma unroll
      for (int j = 0; j < NCOL; ++j) acc[j] += f0 * Ur[j] + f1 * Ur[NCOL + j];
    }
  }
  if (WAL){
    f4v tA = {__expf(acc[0]), __expf(0.2f * acc[0]), __expf(acc[1]), __expf(0.2f * acc[1])};
    *(f4v*)(spqA + (long)n * 4) = tA;                           // as_t0
    f4v tB = {__expf(acc[2]), __expf(0.2f * acc[2]), __expf(acc[3]), __expf(0.2f * acc[3])};
    *(f4v*)(spqB + (long)n * 4) = tB;                           // as_t2
    f4v d1 = {__expf(acc[4]), __expf(0.2f * acc[4]), __expf(acc[5]), __expf(0.2f * acc[5])};
    f4v d2 = {__expf(acc[6]), __expf(0.2f * acc[6]), __expf(acc[7]), __expf(0.2f * acc[7])};
    *(f4v*)(dpq + (long)n * 8) = d1;                            // ad_t1
    *(f4v*)(dpq + (long)n * 8 + 4) = d2;                        // ad_t2
  } else {
    f4v tA = {__expf(acc[0]), __expf(0.2f * acc[0]), __expf(acc[1]), __expf(0.2f * acc[1])};
    *(f4v*)(spqA + (long)n * 4) = tA;                           // as_t1
    f4v d0 = {__expf(acc[2]), __expf(0.2f * acc[2]), __expf(acc[3]), __expf(0.2f * acc[3])};
    *(f4v*)(dpq + (long)n * 4) = d0;                            // ad_t0
  }
}

// ------- exact-count gather round: all loads issued before any use -------
__device__ __forceinline__ void round_load(const int* __restrict__ adj, int j, int cnt,
    const ushort_t* __restrict__ hs, const float* __restrict__ spq, int c0, int hh,
    float2 (&pq)[8], unsigned (&h)[8]){
#pragma unroll
  for (int i = 0; i < 8; ++i){
    if (i < cnt){
      int s = adj[j + i];
      pq[i] = *(const float2*)(spq + s * 4 + hh * 2);
      h[i] = *(const unsigned*)(hs + (long)s * 128 + c0);
    }
  }
}

// ------- transcendental-free softmax accumulate (plain-exp, normalize at end) -------
__device__ __forceinline__ void round_acc(int cnt, float pd, float qd,
    const float2 (&pq)[8], const unsigned (&h)[8], float& n0, float& n1, float& den){
#pragma unroll
  for (int i = 0; i < 8; ++i){
    if (i < cnt){
      float t = pq[i].x * pd, u = pq[i].y * qd;
      float w = t > 1.f ? t : u;     // = exp(leaky_relu(as+ad, 0.2))
      den += w;
      n0 += w * b2f((unsigned short)(h[i] & 0xffffu));
      n1 += w * b2f((unsigned short)(h[i] >> 16));
    }
  }
}

__device__ __forceinline__ void classify_store(float o0, float o1, const void* W, const void* b,
    int lane, long g, void* dout, int fm){
  float w00 = ldf(W, 4 * lane + 0, fm), w01 = ldf(W, 4 * lane + 1, fm);
  float w10 = ldf(W, 4 * lane + 2, fm), w11 = ldf(W, 4 * lane + 3, fm);
  float p0 = o0 * w00 + o1 * w10;
  float p1 = o0 * w01 + o1 * w11;
#pragma unroll
  for (int off = 32; off > 0; off >>= 1){ p0 += __shfl_xor(p0, off, 64); p1 += __shfl_xor(p1, off, 64); }
  if (lane == 0){
    float r0 = p0 + ldf(b, 0, fm);
    float r1 = p1 + ldf(b, 1, fm);
    if (fm){ ((float*)dout)[g * 2] = r0; ((float*)dout)[g * 2 + 1] = r1; }
    else { ((ushort_t*)dout)[g * 2] = f2b(r0); ((ushort_t*)dout)[g * 2 + 1] = f2b(r1); }
  }
}

// ------- token-phase agg body (wave per token node) -------
template<bool FINAL>
__device__ __forceinline__ void agg_tok_body(const int* __restrict__ rowptr, const int* __restrict__ adj,
    const float* __restrict__ atd, const float* __restrict__ spq0, const ushort_t* __restrict__ hs0,
    const void* __restrict__ bsrc, ushort_t* __restrict__ xt_out,
    const void* __restrict__ clsWt, const void* __restrict__ clsbt,
    void* __restrict__ dout, int fm, int db){
  int wv = __builtin_amdgcn_readfirstlane(threadIdx.x >> 6);
  int lane = threadIdx.x & 63;
  int hh = lane >> 5, c0 = lane << 1;
  int d = db * 4 + wv;
  float2 dq = *(const float2*)(atd + (long)d * 4 + hh * 2);   // ad_t0
  int beg = rowptr[d], end = rowptr[d + 1];
  float n0 = 0.f, n1 = 0.f, den = 0.f;
  for (int j = beg; j < end; j += 8){
    int cnt = min(end - j, 8);
    float2 pq[8]; unsigned h[8];
    round_load(adj, j, cnt, hs0, spq0, c0, hh, pq, h);
    round_acc(cnt, dq.x, dq.y, pq, h, n0, n1, den);
  }
  float inv = 1.f / (den + 1e-16f);
  float o0 = n0 * inv + ldf(bsrc, c0, fm);
  float o1 = n1 * inv + ldf(bsrc, c0 + 1, fm);
  o0 = o0 > 0.f ? o0 : __expf(o0) - 1.f;   // ELU
  o1 = o1 > 0.f ? o1 : __expf(o1) - 1.f;
  if (!FINAL){
    unsigned pack = (unsigned)f2b(o0) | ((unsigned)f2b(o1) << 16);
    *(unsigned*)(xt_out + (long)d * 128 + c0) = pack;
  } else {
    classify_store(o0, o1, clsWt, clsbt, lane, (long)NW + d, dout, fm);
  }
}

// ------- wallet-phase agg body: both streams, first rounds' loads fused -------
template<bool FINAL>
__device__ __forceinline__ void agg_wal_body(const int* __restrict__ rowptr, const int* __restrict__ adj,
    const float* __restrict__ awd, const float* __restrict__ spq1, const float* __restrict__ spq2,
    const ushort_t* __restrict__ hs1, const ushort_t* __restrict__ hs2,
    const void* __restrict__ bsrc, ushort_t* __restrict__ xw_out,
    const void* __restrict__ clsWw, const void* __restrict__ clsbw,
    void* __restrict__ dout, int fm, int db){
  int wv = __builtin_amdgcn_readfirstlane(threadIdx.x >> 6);
  int lane = threadIdx.x & 63;
  int hh = lane >> 5, c0 = lane << 1;
  int d = db * 4 + wv;
  float2 dq1 = *(const float2*)(awd + (long)d * 8 + hh * 2);      // ad_t1
  float2 dq2 = *(const float2*)(awd + (long)d * 8 + 4 + hh * 2);  // ad_t2
  int s1 = NT + d, s2 = NT + NW + d;
  int b1 = rowptr[s1], e1 = rowptr[s1 + 1];
  int b2 = rowptr[s2], e2 = rowptr[s2 + 1];
  int c1 = min(e1 - b1, 8), c2 = min(e2 - b2, 8);
  float n10 = 0.f, n11 = 0.f, den1 = 0.f;
  float n20 = 0.f, n21 = 0.f, den2 = 0.f;
  {
    float2 pq1[8], pq2[8]; unsigned h1[8], h2[8];
    if (c1 > 0) round_load(adj, b1, c1, hs1, spq1, c0, hh, pq1, h1);
    if (c2 > 0) round_load(adj, b2, c2, hs2, spq2, c0, hh, pq2, h2);
    if (c1 > 0) round_acc(c1, dq1.x, dq1.y, pq1, h1, n10, n11, den1);
    if (c2 > 0) round_acc(c2, dq2.x, dq2.y, pq2, h2, n20, n21, den2);
  }
  for (int j = b1 + 8; j < e1; j += 8){   // rare tails (deg > 8)
    int cnt = min(e1 - j, 8);
    float2 pq[8]; unsigned h[8];
    round_load(adj, j, cnt, hs1, spq1, c0, hh, pq, h);
    round_acc(cnt, dq1.x, dq1.y, pq, h, n10, n11, den1);
  }
  for (int j = b2 + 8; j < e2; j += 8){
    int cnt = min(e2 - j, 8);
    float2 pq[8]; unsigned h[8];
    round_load(adj, j, cnt, hs2, spq2, c0, hh, pq, h);
    round_acc(cnt, dq2.x, dq2.y, pq, h, n20, n21, den2);
  }
  float i1v = 1.f / (den1 + 1e-16f), i2v = 1.f / (den2 + 1e-16f);
  float o0 = n10 * i1v + n20 * i2v + ldf(bsrc, 128 + c0, fm)     + ldf(bsrc, 256 + c0, fm);
  float o1 = n11 * i1v + n21 * i2v + ldf(bsrc, 128 + c0 + 1, fm) + ldf(bsrc, 256 + c0 + 1, fm);
  o0 = o0 > 0.f ? o0 : __expf(o0) - 1.f;   // ELU
  o1 = o1 > 0.f ? o1 : __expf(o1) - 1.f;
  if (!FINAL){
    unsigned pack = (unsigned)f2b(o0) | ((unsigned)f2b(o1) << 16);
    *(unsigned*)(xw_out + (long)d * 128 + c0) = pack;
  } else {
    classify_store(o0, o1, clsWw, clsbw, lane, (long)d, dout, fm);
  }
}

// ------- merged per-layer agg (agg-VGPR-class ONLY): wallet range first (longest work
// first minimizes tail), token range second; one launch keeps line-fill saturated -------
template<bool FINAL>
__global__ __launch_bounds__(256) void agg_all(const int* __restrict__ rowptr, const int* __restrict__ adj,
    const float* __restrict__ awd, const float* __restrict__ atd,
    const float* __restrict__ spq0, const float* __restrict__ spq1, const float* __restrict__ spq2,
    const ushort_t* __restrict__ hs0, const ushort_t* __restrict__ hs1, const ushort_t* __restrict__ hs2,
    const void* __restrict__ bsrc, ushort_t* __restrict__ xt_out, ushort_t* __restrict__ xw_out,
    const void* __restrict__ clsWw, const void* __restrict__ clsbw,
    const void* __restrict__ clsWt, const void* __restrict__ clsbt,
    void* __restrict__ dout, const int* __restrict__ mode){
  int fm = mode[1];
  int b = blockIdx.x;
  if (b < WGRID){
    agg_wal_body<FINAL>(rowptr, adj, awd, spq1, spq2, hs1, hs2, bsrc, xw_out,
                        clsWw, clsbw, dout, fm, b);
  } else {
    agg_tok_body<FINAL>(rowptr, adj, atd, spq0, hs0, bsrc, xt_out,
                        clsWt, clsbt, dout, fm, b - WGRID);
  }
}

// ====== merged launches: GEMM-VGPR-class bodies only (never merged with agg) ======

// L-A: transpose(512) + uprep(9)
__global__ __launch_bounds__(256) void k_tu(TDesc8 td,
    const void* Wsrc0, const void* Wdst0, const void* atts0, const void* attd0,
    const void* Wsrc1, const void* Wdst1, const void* atts1, const void* attd1,
    float* Uw0, float* Ut0, float* Uw1, float* Ut1, const int* mode){
  int b = blockIdx.x, fm = mode[1];
  if (b < 512){ transpose_body(td, fm, b); return; }
  uprep_body(Wsrc0, Wdst0, atts0, attd0, Wsrc1, Wdst1, atts1, attd1,
             Uw0, Ut0, Uw1, Ut1, fm, (b - 512) * 256 + (int)threadIdx.x);
}

// L-B: in-proj gemms (512+256) || hist (grid-stride)
__global__ __launch_bounds__(256, 2) void k_pre(
    const void* xw_in, const ushort_t* BtLw, const void* lwb, ushort_t* xw0,
    const void* xt_in, const ushort_t* BtLt, const void* ltb, ushort_t* xt0,
    const int* ewt, const int* etw, const int* eww, int* deg,
    const int* mode, int ncW, int ncT){
  int b = blockIdx.x;
  if (b < 512){ gemm_body<128, 64, 64, true, true>(xw_in, BtLw, lwb, xw0, NW, mode[1], ncW, b, 512); return; }
  b -= 512;
  if (b < 256){ gemm_body<64, 64, 64, true, true>(xt_in, BtLt, ltb, xt0, NT, mode[1], ncT, b, 256); return; }
  b -= 256;
  hist_loop(ewt, etw, eww, mode[0], deg, b, HGRID);
}

// L-C: ALL THREE hs gemms L0 (512+256+384) || fill (grid-stride) || a_kerns (782+391)
__global__ __launch_bounds__(256, 2) void k_gemms0(
    const ushort_t* xw0, const ushort_t* xt0,
    const ushort_t* BtS0w, const ushort_t* BtS0t, const ushort_t* BtS0w2,
    ushort_t* hs0, ushort_t* hs1, ushort_t* hs2,
    const float* Uw0, const float* Ut0, float* awd, float* atd,
    float* spq0, float* spq1, float* spq2,
    const int* ewt, const int* etw, const int* eww, int* cursor, int* adj,
    const int* mode, int ncW, int ncT){
  int b = blockIdx.x;
  if (b < 512){ gemm_body<64, 128, 128, false, false>(xw0, BtS0w, nullptr, hs0, NW, 0, ncW, b, 512); return; }
  b -= 512;
  if (b < 256){ gemm_body<64, 128, 128, false, false>(xt0, BtS0t, nullptr, hs1, NT, 0, ncT, b, 256); return; }
  b -= 256;
  if (b < 384){ gemm_body<64, 128, 128, false, false>(xw0, BtS0w2, nullptr, hs2, NW, 0, ncW, b, 384); return; }
  b -= 384;
  if (b < FGRID){ fill_loop(ewt, etw, eww, mode[0], cursor, adj, b, FGRID); return; }
  b -= FGRID;
  if (b < AWG){ a_body<64, true>(xw0, Uw0, awd, spq0, spq2, NW, b * 256 + (int)threadIdx.x); return; }
  b -= AWG;
  a_body<64, false>(xt0, Ut0, atd, spq1, nullptr, NT, b * 256 + (int)threadIdx.x);
}

// L-E: ALL THREE hs gemms L1 (512+256+384) || a_kerns L1 (782+391)
__global__ __launch_bounds__(256, 2) void k_gemms1(
    const ushort_t* xwB, const ushort_t* xtB,
    const ushort_t* BtS1w, const ushort_t* BtS1t, const ushort_t* BtS1w2,
    ushort_t* hs0, ushort_t* hs1, ushort_t* hs2,
    const float* Uw1, const float* Ut1, float* awd, float* atd,
    float* spq0, float* spq1, float* spq2, const int* mode, int ncW, int ncT){
  int b = blockIdx.x;
  if (b < 512){ gemm_body<128, 128, 128, false, false>(xwB, BtS1w, nullptr, hs0, NW, 0, ncW, b, 512); return; }
  b -= 512;
  if (b < 256){ gemm_body<128, 128, 128, false, false>(xtB, BtS1t, nullptr, hs1, NT, 0, ncT, b, 256); return; }
  b -= 256;
  if (b < 384){ gemm_body<128, 128, 128, false, false>(xwB, BtS1w2, nullptr, hs2, NW, 0, ncW, b, 384); return; }
  b -= 384;
  if (b < AWG){ a_body<128, true>(xwB, Uw1, awd, spq0, spq2, NW, b * 256 + (int)threadIdx.x); return; }
  b -= AWG;
  a_body<128, false>(xtB, Ut1, atd, spq1, nullptr, NT, b * 256 + (int)threadIdx.x);
}

extern "C" void kernel_launch(void* const* d_in, const int* in_sizes, int n_in,
                              void* d_out, int out_size, void* d_ws, size_t ws_size,
                              hipStream_t stream){
  const void* x_wallet = d_in[0];
  const void* x_token  = d_in[1];
  const void* lin_w_W  = d_in[2];
  const void* lin_w_b  = d_in[3];
  const void* lin_t_W  = d_in[4];
  const void* lin_t_b  = d_in[5];
  const void* Wsrc0    = d_in[6];
  const void* Wdst0    = d_in[7];
  const void* atts0    = d_in[8];
  const void* attd0    = d_in[9];
  const void* b0       = d_in[10];
  const void* Wsrc1    = d_in[11];
  const void* Wdst1    = d_in[12];
  const void* atts1    = d_in[13];
  const void* attd1    = d_in[14];
  const void* b1       = d_in[15];
  const void* cls_w_W  = d_in[16];
  const void* cls_w_b  = d_in[17];
  const void* cls_t_W  = d_in[18];
  const void* cls_t_b  = d_in[19];
  const int* e_wt = (const int*)d_in[20];
  const int* e_tw = (const int*)d_in[21];
  const int* e_ww = (const int*)d_in[22];

  char* ws = (char*)d_ws;
  size_t off = 0;
  auto alloc = [&](size_t bytes) -> char* {
    char* p = ws + off; off += (bytes + 255) & ~(size_t)255; return p;
  };
  int* rowptr = (int*)alloc((size_t)(NSEG + 1) * 4);
  int* deg    = (int*)alloc((size_t)(NSEG + 1) * 4);   // doubles as fill cursor after scan
  int* adj    = (int*)alloc((size_t)3 * EE * 4);
  int* sums   = (int*)alloc(512 * 4);
  int* mode   = (int*)alloc(8);
  ushort_t* BtLw = (ushort_t*)alloc(64 * 128 * 2);
  ushort_t* BtLt = (ushort_t*)alloc(64 * 64 * 2);
  ushort_t* BtS0 = (ushort_t*)alloc(3 * 128 * 64 * 2);
  ushort_t* BtS1 = (ushort_t*)alloc(3 * 128 * 128 * 2);
  float* Uw0 = (float*)alloc(64 * 8 * 4);
  float* Ut0 = (float*)alloc(64 * 4 * 4);
  float* Uw1 = (float*)alloc(128 * 8 * 4);
  float* Ut1 = (float*)alloc(128 * 4 * 4);
  float* awd = (float*)alloc((size_t)NW * 8 * 4);    // wallet dst-role pq (ad_t1, ad_t2)
  float* atd = (float*)alloc((size_t)NT * 4 * 4);    // token dst-role pq (ad_t0)
  float* spq0 = (float*)alloc((size_t)NW * 4 * 4);   // wallet src-role pq, type0
  float* spq1 = (float*)alloc((size_t)NT * 4 * 4);   // token  src-role pq, type1
  float* spq2 = (float*)alloc((size_t)NW * 4 * 4);   // wallet src-role pq, type2
  ushort_t* hs0 = (ushort_t*)alloc((size_t)NW * 128 * 2);
  ushort_t* hs1 = (ushort_t*)alloc((size_t)NT * 128 * 2);
  ushort_t* hs2 = (ushort_t*)alloc((size_t)NW * 128 * 2);
  ushort_t* xbuf = (ushort_t*)alloc(((size_t)NW + NT) * 128 * 2);
  ushort_t* xw0 = xbuf;
  ushort_t* xt0 = xbuf + (size_t)NW * 64;
  ushort_t* xwB = xbuf;                         // aliases xw0+xt0 (both dead by then)
  ushort_t* xtB = xbuf + (size_t)NW * 128;      // disjoint from xw0/xt0
  (void)in_sizes; (void)n_in;

  if (off > ws_size){
    hipMemsetAsync(d_out, 0, (size_t)out_size * 2, stream);
    return;
  }

  hipMemsetAsync(deg, 0, (size_t)NSEG * 4, stream);
  detect_kern<<<1, 64, 0, stream>>>(e_wt, e_tw, e_ww, (const unsigned*)x_wallet, mode);

  TDesc8 td;
  td.d[0] = { lin_w_W, BtLw, 0, 128, 64 };
  td.d[1] = { lin_t_W, BtLt, 0, 64, 64 };
  for (int t = 0; t < 3; ++t){
    td.d[2 + t] = { Wsrc0, BtS0 + t * 128 * 64,  (long)t * 64 * 128,  64,  128 };
    td.d[5 + t] = { Wsrc1, BtS1 + t * 128 * 128, (long)t * 128 * 128, 128, 128 };
  }
  int ncW = (NW + 127) / 128, ncT = (NT + 127) / 128;

  k_tu<<<521, 256, 0, stream>>>(td, Wsrc0, Wdst0, atts0, attd0, Wsrc1, Wdst1, atts1, attd1,
                                Uw0, Ut0, Uw1, Ut1, mode);
  k_pre<<<512 + 256 + HGRID, 256, 0, stream>>>(x_wallet, BtLw, lin_w_b, xw0,
                                               x_token, BtLt, lin_t_b, xt0,
                                               e_wt, e_tw, e_ww, deg, mode, ncW, ncT);
  int nch = (NSEG + 1023) / 1024;
  scan1<<<nch, 512, 0, stream>>>(deg, rowptr, sums);
  scan2<<<1, 512, 0, stream>>>(sums, nch);
  scan3<<<(NSEG + 255) / 256, 256, 0, stream>>>(rowptr, deg, sums);   // deg becomes cursor

  // ---- layer 0: GEMM-class mega-launch, then ONE agg-class launch (wal ∥ tok) ----
  k_gemms0<<<512 + 256 + 384 + FGRID + AWG + ATG, 256, 0, stream>>>(xw0, xt0,
      BtS0, BtS0 + 128 * 64, BtS0 + 2 * 128 * 64, hs0, hs1, hs2,
      Uw0, Ut0, awd, atd, spq0, spq1, spq2, e_wt, e_tw, e_ww, deg, adj, mode, ncW, ncT);
  agg_all<false><<<WGRID + TGRID, 256, 0, stream>>>(rowptr, adj, awd, atd, spq0, spq1, spq2,
      hs0, hs1, hs2, b0, xtB, xwB, nullptr, nullptr, nullptr, nullptr, nullptr, mode);

  // ---- layer 1 (classifier fused) ----
  k_gemms1<<<512 + 256 + 384 + AWG + ATG, 256, 0, stream>>>(xwB, xtB,
      BtS1, BtS1 + 128 * 128, BtS1 + 2 * 128 * 128, hs0, hs1, hs2,
      Uw1, Ut1, awd, atd, spq0, spq1, spq2, mode, ncW, ncT);
  agg_all<true><<<WGRID + TGRID, 256, 0, stream>>>(rowptr, adj, awd, atd, spq0, spq1, spq2,
      hs0, hs1, hs2, b1, nullptr, nullptr, cls_w_W, cls_w_b, cls_t_W, cls_t_b, d_out, mode);
}